// Round 2
// baseline (493.796 us; speedup 1.0000x reference)
//
#include <hip/hip_runtime.h>

#define Bc 2
#define Sc 2048
#define Dc 2048
#define Hc 16
#define DHc 128

typedef _Float16 f16;
typedef __attribute__((ext_vector_type(4))) _Float16 v4h;
typedef __attribute__((ext_vector_type(8))) _Float16 v8h;
typedef __attribute__((ext_vector_type(4))) float v4f;
typedef __attribute__((ext_vector_type(16))) float v16f;
typedef __attribute__((ext_vector_type(4))) float f32x4;

// ---------------------------------------------------------------------------
// Convert f32 inputs -> f16 once.
// ---------------------------------------------------------------------------
__global__ void cvt_kernel(const float* __restrict__ x, const float* __restrict__ wq,
                           const float* __restrict__ wk, const float* __restrict__ wv,
                           f16* __restrict__ xh, f16* __restrict__ wqh,
                           f16* __restrict__ wkh, f16* __restrict__ wvh)
{
    int bid = blockIdx.x;
    const float* src; f16* dst; int idx;
    if (bid < 8192)       { src = x;  dst = xh;  idx = bid; }
    else if (bid < 12288) { src = wq; dst = wqh; idx = bid - 8192; }
    else if (bid < 16384) { src = wk; dst = wkh; idx = bid - 12288; }
    else                  { src = wv; dst = wvh; idx = bid - 16384; }
    int i = idx * 256 + threadIdx.x;
    f32x4 v = ((const f32x4*)src)[i];
    v4h hv; hv[0]=(f16)v[0]; hv[1]=(f16)v[1]; hv[2]=(f16)v[2]; hv[3]=(f16)v[3];
    ((v4h*)dst)[i] = hv;
}

// ---------------------------------------------------------------------------
// Fused QKV projection GEMM C[4096][6144] = X . [wq;wk;wv]^T.
// 128x256 tile, BK=64, 8 waves, 768 blocks (= exactly 3 balanced rounds).
// This round: TRUE deep pipeline (T3/T4) —
//   * 3 LDS buffers (144 KB), STAGE(t+3) issued at iter top
//   * raw s_barrier + counted s_waitcnt vmcnt(12/6/0)  (never drain mid-loop)
//   * frag read-ahead: RDFRAG(t+1) and MM(t) share a barrier window so the
//     compiler hides ds_read latency under the 32 MFMAs; lgkmcnt(0) lands
//     after the MFMA cluster where it is ~free.
// T2 XOR-swizzle (source-permuted gload_lds + swizzled ds_read) kept.
// ---------------------------------------------------------------------------
__launch_bounds__(512, 2)
__global__ void proj256_kernel(const f16* __restrict__ xh, const f16* __restrict__ wall,
                               const float* __restrict__ cs, const float* __restrict__ sn,
                               f16* __restrict__ qh, f16* __restrict__ kh,
                               f16* __restrict__ vt)
{
    const int bid = blockIdx.x;
    const int swz = (bid & 7) * 96 + (bid >> 3);     // 768 % 8 == 0 -> bijective
    const int mt = swz & 31, nt = swz >> 5;
    const int m0 = mt * 128, n0 = nt * 256;

    const int tid = threadIdx.x;
    const int wid = tid >> 6, lane = tid & 63;
    const int wr = wid >> 2, wc = wid & 3;           // 2 x 4 waves
    const int l15 = lane & 15, quad = lane >> 4;
    const int x7 = l15 & 7;

    // LDS: 3 buffers x (A 128x64 + B 256x64) halves = 147456 B
    __shared__ __align__(16) f16 lds[73728];

    const f16* aS[2]; const f16* bS[4];
    #pragma unroll
    for (int j = 0; j < 2; ++j) {
        int c = tid + j * 512;
        int r = c >> 3, s = c & 7;
        aS[j] = xh + (size_t)(m0 + r) * Dc + ((s ^ (r & 7)) * 8);
    }
    #pragma unroll
    for (int j = 0; j < 4; ++j) {
        int c = tid + j * 512;
        int r = c >> 3, s = c & 7;
        bS[j] = wall + (size_t)(n0 + r) * Dc + ((s ^ (r & 7)) * 8);
    }

#define STAGE(kt_, buf_) do {                                                   \
        const int _ko = (kt_) * 64;                                             \
        f16* _b = lds + (buf_) * 24576;                                         \
        _Pragma("unroll")                                                       \
        for (int j = 0; j < 2; ++j)                                             \
            __builtin_amdgcn_global_load_lds(                                   \
                (const __attribute__((address_space(1))) void*)(aS[j] + _ko),   \
                (__attribute__((address_space(3))) void*)(_b + j * 4096 + wid * 512), \
                16, 0, 0);                                                      \
        _Pragma("unroll")                                                       \
        for (int j = 0; j < 4; ++j)                                             \
            __builtin_amdgcn_global_load_lds(                                   \
                (const __attribute__((address_space(1))) void*)(bS[j] + _ko),   \
                (__attribute__((address_space(3))) void*)(_b + 8192 + j * 4096 + wid * 512), \
                16, 0, 0);                                                      \
    } while (0)

#define RDFRAG(af_, bf_, buf_) do {                                             \
        const f16* _Ab = lds + (buf_) * 24576;                                  \
        const f16* _Bb = _Ab + 8192;                                            \
        _Pragma("unroll")                                                       \
        for (int kk = 0; kk < 2; ++kk) {                                        \
            _Pragma("unroll")                                                   \
            for (int mi = 0; mi < 4; ++mi)                                      \
                af_[kk][mi] = *(const v8h*)(_Ab + (wr * 64 + mi * 16 + l15) * 64 \
                                            + (((kk * 4 + quad) ^ x7) * 8));    \
            _Pragma("unroll")                                                   \
            for (int ni = 0; ni < 4; ++ni)                                      \
                bf_[kk][ni] = *(const v8h*)(_Bb + (wc * 64 + ni * 16 + l15) * 64 \
                                            + (((kk * 4 + quad) ^ x7) * 8));    \
        }                                                                       \
    } while (0)

#define MM(af_, bf_) do {                                                       \
        __builtin_amdgcn_s_setprio(1);                                          \
        _Pragma("unroll")                                                       \
        for (int kk = 0; kk < 2; ++kk)                                          \
            _Pragma("unroll")                                                   \
            for (int mi = 0; mi < 4; ++mi)                                      \
                _Pragma("unroll")                                               \
                for (int ni = 0; ni < 4; ++ni)                                  \
                    acc[mi][ni] = __builtin_amdgcn_mfma_f32_16x16x32_f16(       \
                        af_[kk][mi], bf_[kk][ni], acc[mi][ni], 0, 0, 0);        \
        __builtin_amdgcn_s_setprio(0);                                          \
    } while (0)

#define VMW12 asm volatile("s_waitcnt vmcnt(12)" ::: "memory")
#define VMW6  asm volatile("s_waitcnt vmcnt(6)"  ::: "memory")
#define VMW0  asm volatile("s_waitcnt vmcnt(0)"  ::: "memory")
#define LGKM0 asm volatile("s_waitcnt lgkmcnt(0)" ::: "memory")
#define BAR   __builtin_amdgcn_s_barrier()

    v4f acc[4][4];
    #pragma unroll
    for (int i = 0; i < 4; ++i)
        #pragma unroll
        for (int j = 0; j < 4; ++j)
            acc[i][j] = (v4f){0.f, 0.f, 0.f, 0.f};

    v8h afA[2][4], bfA[2][4], afB[2][4], bfB[2][4];

    // prologue: fill 3-deep pipe, read tile0 frags
    STAGE(0, 0);
    STAGE(1, 1);
    STAGE(2, 2);
    VMW12;                       // stage0 landed (12 newer outstanding)
    BAR;
    RDFRAG(afA, bfA, 0);
    LGKM0;
    BAR;                         // all waves done reading buf0

    #pragma unroll 1
    for (int t = 0; t < 32; t += 2) {
        const int bufc  = t % 3;
        const int bufn  = (t + 1) % 3;
        const int bufn2 = (t + 2) % 3;

        // even: stage t+3 -> buf[t%3]; compute tile t (set A); read t+1 (set B)
        if (t + 3 < 32) STAGE(t + 3, bufc);
        if (t <= 28) { VMW12; } else { VMW0; }   // stage(t+1) landed
        BAR;
        RDFRAG(afB, bfB, bufn);
        MM(afA, bfA);            // no dep on RDFRAG -> MFMA hides ds_read latency
        LGKM0;
        BAR;                     // reads of buf[t+1] done -> may be overwritten

        // odd: stage t+4 -> buf[(t+1)%3]; compute t+1 (set B); read t+2 (set A)
        if (t + 4 < 32) STAGE(t + 4, bufn);
        if (t + 2 < 32) {
            if (t <= 26) { VMW12; } else { VMW6; }   // stage(t+2) landed
            BAR;
            RDFRAG(afA, bfA, bufn2);
            MM(afB, bfB);
            LGKM0;
            BAR;
        } else {
            MM(afB, bfB);        // tile 31: pipe drained, regs already loaded
        }
    }

#undef STAGE
#undef RDFRAG
#undef MM
#undef VMW12
#undef VMW6
#undef VMW0
#undef LGKM0
#undef BAR

    __syncthreads();

    // ---------------- epilogue (z uniform per block: BN=256 | 2048) ---------
    const int z = n0 >> 11;
    const int bb = m0 >> 11, s0 = m0 & 2047;

    if (z < 2) {
        f16 (*Ep)[264] = (f16(*)[264])lds;
        #pragma unroll
        for (int mi = 0; mi < 4; ++mi)
            #pragma unroll
            for (int ni = 0; ni < 4; ++ni)
                #pragma unroll
                for (int r = 0; r < 4; ++r)
                    Ep[wr * 64 + mi * 16 + quad * 4 + r][wc * 64 + ni * 16 + l15] =
                        (f16)acc[mi][ni][r];
        __syncthreads();
        f16* outp = (z == 0) ? qh : kh;
        const float scl = (z == 0) ? 0.08838834764831845f : 1.0f;
        #pragma unroll
        for (int it = 0; it < 8; ++it) {
            int ch = tid + it * 512, row = ch >> 5, c = ch & 31;
            v8h val = *(const v8h*)&Ep[row][c * 8];
            int s = s0 + row;
            int nn = (n0 & 2047) + c * 8;
            int h = nn >> 7, d0 = nn & 127;
            const float* cp = cs + (size_t)s * DHc + d0;
            const float* sp = sn + (size_t)s * DHc + d0;
            f32x4 ca = *(const f32x4*)cp, cb = *(const f32x4*)(cp + 4);
            f32x4 sa = *(const f32x4*)sp, sb = *(const f32x4*)(sp + 4);
            float v[8];
            #pragma unroll
            for (int j = 0; j < 8; ++j) v[j] = (float)val[j];
            v8h rv;
            rv[0] = (f16)((v[0]*ca[0] - v[1]*sa[0]) * scl);
            rv[1] = (f16)((v[1]*ca[1] + v[0]*sa[1]) * scl);
            rv[2] = (f16)((v[2]*ca[2] - v[3]*sa[2]) * scl);
            rv[3] = (f16)((v[3]*ca[3] + v[2]*sa[3]) * scl);
            rv[4] = (f16)((v[4]*cb[0] - v[5]*sb[0]) * scl);
            rv[5] = (f16)((v[5]*cb[1] + v[4]*sb[1]) * scl);
            rv[6] = (f16)((v[6]*cb[2] - v[7]*sb[2]) * scl);
            rv[7] = (f16)((v[7]*cb[3] + v[6]*sb[3]) * scl);
            *(v8h*)(outp + ((size_t)(bb * Hc + h) * Sc + s) * DHc + d0) = rv;
        }
    } else {
        f16 (*Ep)[136] = (f16(*)[136])lds;
        #pragma unroll
        for (int mi = 0; mi < 4; ++mi)
            #pragma unroll
            for (int ni = 0; ni < 4; ++ni)
                #pragma unroll
                for (int r = 0; r < 4; ++r)
                    Ep[wc * 64 + ni * 16 + l15][wr * 64 + mi * 16 + quad * 4 + r] =
                        (f16)acc[mi][ni][r];
        __syncthreads();
        #pragma unroll
        for (int it = 0; it < 8; ++it) {
            int ch = tid + it * 512, n = ch >> 4, cm = ch & 15;
            int nn = (n0 & 2047) + n;
            int h = nn >> 7, d = nn & 127;
            int s = s0 + cm * 8;
            *(v8h*)(vt + ((size_t)(bb * Hc + h) * DHc + d) * Sc + s) =
                *(const v8h*)&Ep[n][cm * 8];
        }
    }
}

// ---------------------------------------------------------------------------
// Fallback proj (ws too small) + separate rope.
// ---------------------------------------------------------------------------
__launch_bounds__(256)
__global__ void proj_kernel(const float* __restrict__ x, const float* __restrict__ wq,
                            const float* __restrict__ wk, const float* __restrict__ wv,
                            f16* __restrict__ qh, f16* __restrict__ kh, f16* __restrict__ vt)
{
    const int z = blockIdx.z;
    const float* w = (z == 0) ? wq : ((z == 1) ? wk : wv);
    const int m0 = blockIdx.x * 128, n0 = blockIdx.y * 128;
    const int tid = threadIdx.x, lane = tid & 63, wid = tid >> 6;
    const int wm = wid >> 1, wn = wid & 1;
    const int l15 = lane & 15, quad = lane >> 4;

    __shared__ __align__(16) f16 smem[2 * 128 * 72];
    f16 (*As)[72] = (f16(*)[72])smem;
    f16 (*Bs)[72] = (f16(*)[72])(smem + 128 * 72);

    v4f acc[4][4];
    for (int i = 0; i < 4; ++i)
        for (int j = 0; j < 4; ++j)
            acc[i][j] = (v4f){0.f, 0.f, 0.f, 0.f};

    for (int k0 = 0; k0 < Dc; k0 += 64) {
        __syncthreads();
        for (int it = 0; it < 4; ++it) {
            int chunk = tid + it * 256;
            int r = chunk >> 3, cc = chunk & 7;
            const f32x4* pa = (const f32x4*)(x + (size_t)(m0 + r) * Dc + k0 + cc * 8);
            f32x4 a0 = pa[0], a1 = pa[1];
            v8h ha;
            ha[0]=(f16)a0[0]; ha[1]=(f16)a0[1]; ha[2]=(f16)a0[2]; ha[3]=(f16)a0[3];
            ha[4]=(f16)a1[0]; ha[5]=(f16)a1[1]; ha[6]=(f16)a1[2]; ha[7]=(f16)a1[3];
            *(v8h*)&As[r][cc * 8] = ha;
            const f32x4* pb = (const f32x4*)(w + (size_t)(n0 + r) * Dc + k0 + cc * 8);
            f32x4 b0 = pb[0], b1 = pb[1];
            v8h hb;
            hb[0]=(f16)b0[0]; hb[1]=(f16)b0[1]; hb[2]=(f16)b0[2]; hb[3]=(f16)b0[3];
            hb[4]=(f16)b1[0]; hb[5]=(f16)b1[1]; hb[6]=(f16)b1[2]; hb[7]=(f16)b1[3];
            *(v8h*)&Bs[r][cc * 8] = hb;
        }
        __syncthreads();
        for (int kk = 0; kk < 2; ++kk) {
            v8h af[4], bf[4];
            for (int mi = 0; mi < 4; ++mi)
                af[mi] = *(const v8h*)&As[wm * 64 + mi * 16 + l15][kk * 32 + quad * 8];
            for (int ni = 0; ni < 4; ++ni)
                bf[ni] = *(const v8h*)&Bs[wn * 64 + ni * 16 + l15][kk * 32 + quad * 8];
            for (int mi = 0; mi < 4; ++mi)
                for (int ni = 0; ni < 4; ++ni)
                    acc[mi][ni] = __builtin_amdgcn_mfma_f32_16x16x32_f16(
                        af[mi], bf[ni], acc[mi][ni], 0, 0, 0);
        }
    }
    __syncthreads();
    f16 (*Ep)[136] = (f16(*)[136])smem;
    for (int mi = 0; mi < 4; ++mi)
        for (int ni = 0; ni < 4; ++ni)
            for (int r = 0; r < 4; ++r) {
                int ml = wm * 64 + mi * 16 + quad * 4 + r;
                int nl = wn * 64 + ni * 16 + l15;
                f16 val = (f16)acc[mi][ni][r];
                if (z == 2) Ep[nl][ml] = val;
                else        Ep[ml][nl] = val;
            }
    __syncthreads();
    const int b = m0 >> 11, s0 = m0 & 2047, h = n0 >> 7;
    if (z < 2) {
        f16* outp = (z == 0) ? qh : kh;
        for (int it = 0; it < 8; ++it) {
            int ch = tid + it * 256, row = ch >> 4, c = ch & 15;
            *(v8h*)(outp + ((size_t)((b * Hc + h) * Sc) + s0 + row) * DHc + c * 8) =
                *(const v8h*)&Ep[row][c * 8];
        }
    } else {
        for (int it = 0; it < 8; ++it) {
            int ch = tid + it * 256, row = ch >> 4, c = ch & 15;
            *(v8h*)(vt + ((size_t)((b * Hc + h) * DHc) + row) * Sc + s0 + c * 8) =
                *(const v8h*)&Ep[row][c * 8];
        }
    }
}

__global__ void rope_kernel(f16* __restrict__ qh, f16* __restrict__ kh,
                            const float* __restrict__ cs, const float* __restrict__ sn)
{
    int i  = blockIdx.x * 256 + threadIdx.x;
    int d2 = i & 63;
    int s  = (i >> 6) & (Sc - 1);
    int bh = i >> 17;
    f16* t = blockIdx.y ? kh : qh;
    float scale = blockIdx.y ? 1.0f : 0.08838834764831845f;
    float c  = cs[s * DHc + 2 * d2];
    float sv = sn[s * DHc + 2 * d2];
    f16* p = t + ((size_t)bh * Sc + s) * DHc + 2 * d2;
    float t0 = (float)p[0], t1 = (float)p[1];
    p[0] = (f16)((t0 * c - t1 * sv) * scale);
    p[1] = (f16)((t1 * c + t0 * sv) * scale);
}

// ---------------------------------------------------------------------------
// Flash attention v6: balanced + XCD-local (unchanged this round).
// ---------------------------------------------------------------------------
__launch_bounds__(256, 2)
__global__ void attn_kernel(const f16* __restrict__ qh, const f16* __restrict__ kh,
                            const f16* __restrict__ vt, float* __restrict__ out)
{
    const int L = blockIdx.x;
    const int slot = L >> 3;
    const int bh = (L & 7) * 4 + (slot >> 3);
    const int p  = slot & 7;
    const int b = bh >> 4, h = bh & 15;
    const int tid = threadIdx.x, lane = tid & 63, w = tid >> 6;
    const int l31 = lane & 31, half = lane >> 5;
    const int sw = l31 & 7;

    __shared__ __align__(16) f16 smem[32768];     // K dbuf 32KB + V dbuf 32KB
    f16* ksm = smem;
    f16* vsm = smem + 16384;

    const size_t bhoff = (size_t)bh * Sc * DHc;

    const f16* ksrc[4]; const f16* vsrc[4];
    f16* kdst[4]; f16* vdst[4];
    #pragma unroll
    for (int j = 0; j < 4; ++j) {
        int slot0 = j * 256 + w * 64;
        {   int r = (slot0 >> 4) + (lane >> 4);
            int c = (lane & 15) ^ (r & 7);
            ksrc[j] = kh + bhoff + (size_t)r * DHc + c * 8;
            kdst[j] = ksm + slot0 * 8; }
        {   int r = (slot0 >> 3) + (lane >> 3);
            int c = (lane & 7) ^ (r & 7);
            vsrc[j] = vt + bhoff + (size_t)r * Sc + c * 8;
            vdst[j] = vsm + slot0 * 8; }
    }

#define STAGE(kt_, buf_) do {                                                   \
        int _ko = (kt_) * 64 * DHc;                                             \
        int _vo = (kt_) * 64;                                                   \
        int _lb = (buf_) * 8192;                                                \
        _Pragma("unroll")                                                       \
        for (int j = 0; j < 4; ++j) {                                           \
            __builtin_amdgcn_global_load_lds(                                   \
                (const __attribute__((address_space(1))) void*)(ksrc[j] + _ko), \
                (__attribute__((address_space(3))) void*)(kdst[j] + _lb), 16, 0, 0); \
            __builtin_amdgcn_global_load_lds(                                   \
                (const __attribute__((address_space(1))) void*)(vsrc[j] + _vo), \
                (__attribute__((address_space(3))) void*)(vdst[j] + _lb), 16, 0, 0); \
        } } while (0)

    const int qtA = 15 - p;
    const int nktA = 2 * qtA + 2;     // + nktB = 34 for every block

    int ibuf = 0;
    STAGE(0, 0);

    #pragma unroll 1
    for (int ph = 0; ph < 2; ++ph) {
        const int qt  = ph ? p : qtA;
        const int nkt = 2 * qt + 2;
        const int q0  = qt * 128 + w * 32;
        const int qg  = q0 + l31;

        v8h qf[8];
        const f16* qrow = qh + bhoff + (size_t)qg * DHc;
        #pragma unroll
        for (int s = 0; s < 8; ++s)
            qf[s] = *(const v8h*)(qrow + s * 16 + half * 8);

        float l_run = 0.f;
        v16f o[4];
        #pragma unroll
        for (int i = 0; i < 4; ++i)
            #pragma unroll
            for (int r = 0; r < 16; ++r) o[i][r] = 0.f;

        #pragma unroll 1
        for (int kt = 0; kt < nkt; ++kt, ++ibuf) {
            __syncthreads();             // publishes buf[ibuf&1]
            const int buf = ibuf & 1;
            const int ni = ibuf + 1;
            if (ni < 34) {
                int tn = (ni < nktA) ? ni : ni - nktA;
                STAGE(tn, ni & 1);
            }
            if (q0 + 31 < kt * 64) continue;   // fully masked; barriers uniform

            const f16* kbuf = ksm + buf * 8192;
            const f16* vbuf = vsm + buf * 8192;
            const bool do1 = (kt * 64 + 32 <= q0 + 31);

            v16f st0, st1;
            #pragma unroll
            for (int r = 0; r < 16; ++r) { st0[r] = 0.f; st1[r] = 0.f; }
            #pragma unroll
            for (int s = 0; s < 8; ++s) {
                int c = ((s * 2 + half) ^ sw) * 8;
                v8h kf0 = *(const v8h*)(kbuf + l31 * 128 + c);
                st0 = __builtin_amdgcn_mfma_f32_32x32x16_f16(kf0, qf[s], st0, 0, 0, 0);
                if (do1) {
                    v8h kf1 = *(const v8h*)(kbuf + (32 + l31) * 128 + c);
                    st1 = __builtin_amdgcn_mfma_f32_32x32x16_f16(kf1, qf[s], st1, 0, 0, 0);
                }
            }

            float sum = 0.f;
            #pragma unroll
            for (int r = 0; r < 16; ++r) {
                int key = kt * 64 + (r & 3) + 8 * (r >> 2) + 4 * half;
                float sv = (key > qg) ? -1e30f : st0[r];
                float pe = __expf(sv);
                st0[r] = pe; sum += pe;
            }
            if (do1) {
                #pragma unroll
                for (int r = 0; r < 16; ++r) {
                    int key = kt * 64 + 32 + (r & 3) + 8 * (r >> 2) + 4 * half;
                    float sv = (key > qg) ? -1e30f : st1[r];
                    float pe = __expf(sv);
                    st1[r] = pe; sum += pe;
                }
            }
            sum += __shfl_xor(sum, 32);
            l_run += sum;

            #pragma unroll
            for (int s2 = 0; s2 < 4; ++s2) {
                v4h bfr;
                bfr[0]=(f16)st0[4*s2]; bfr[1]=(f16)st0[4*s2+1];
                bfr[2]=(f16)st0[4*s2+2]; bfr[3]=(f16)st0[4*s2+3];
                int c = ((s2 ^ sw) * 8) + half * 4;
                #pragma unroll
                for (int dt = 0; dt < 4; ++dt) {
                    v4h vf = *(const v4h*)(vbuf + (dt * 32 + l31) * 64 + c);
                    o[dt] = __builtin_amdgcn_mfma_f32_32x32x8f16(vf, bfr, o[dt], 0, 0, 0);
                }
            }
            if (do1) {
                #pragma unroll
                for (int s2 = 0; s2 < 4; ++s2) {
                    v4h bfr;
                    bfr[0]=(f16)st1[4*s2]; bfr[1]=(f16)st1[4*s2+1];
                    bfr[2]=(f16)st1[4*s2+2]; bfr[3]=(f16)st1[4*s2+3];
                    int c = (((4 + s2) ^ sw) * 8) + half * 4;
                    #pragma unroll
                    for (int dt = 0; dt < 4; ++dt) {
                        v4h vf = *(const v4h*)(vbuf + (dt * 32 + l31) * 64 + c);
                        o[dt] = __builtin_amdgcn_mfma_f32_32x32x8f16(vf, bfr, o[dt], 0, 0, 0);
                    }
                }
            }
        }

        float inv = 1.f / l_run;
        float mxd = -1e30f;
        #pragma unroll
        for (int dt = 0; dt < 4; ++dt)
            #pragma unroll
            for (int r = 0; r < 16; ++r) {
                o[dt][r] *= inv;
                mxd = fmaxf(mxd, o[dt][r]);
            }
        mxd = fmaxf(mxd, __shfl_xor(mxd, 32));
        float sd = 0.f;
        #pragma unroll
        for (int dt = 0; dt < 4; ++dt)
            #pragma unroll
            for (int r = 0; r < 16; ++r) {
                float t = __expf(o[dt][r] - mxd);
                o[dt][r] = t;
                sd += t;
            }
        sd += __shfl_xor(sd, 32);
        float rinv = 1.f / sd;

        float* orow = out + (size_t)(b * Sc + qg) * Dc + h * DHc;
        #pragma unroll
        for (int dt = 0; dt < 4; ++dt)
            #pragma unroll
            for (int g = 0; g < 4; ++g) {
                f32x4 vv;
                vv[0] = o[dt][4*g+0] * rinv;
                vv[1] = o[dt][4*g+1] * rinv;
                vv[2] = o[dt][4*g+2] * rinv;
                vv[3] = o[dt][4*g+3] * rinv;
                *(f32x4*)(orow + dt * 32 + g * 8 + half * 4) = vv;
            }
    }
#undef STAGE
}

extern "C" void kernel_launch(void* const* d_in, const int* in_sizes, int n_in,
                              void* d_out, int out_size, void* d_ws, size_t ws_size,
                              hipStream_t stream)
{
    const float* x  = (const float*)d_in[0];
    const float* wq = (const float*)d_in[1];
    const float* wk = (const float*)d_in[2];
    const float* wv = (const float*)d_in[3];
    const float* cs = (const float*)d_in[4];
    const float* sn = (const float*)d_in[5];
    float* out = (float*)d_out;

    const size_t tsz = (size_t)Bc * Hc * Sc * DHc;   // 8,388,608 halves
    f16* qh = (f16*)d_ws;
    f16* kh = qh + tsz;
    f16* vt = kh + tsz;

    if (ws_size >= 11 * tsz) {
        f16* xh  = vt + tsz;
        f16* wqh = xh + tsz;
        f16* wkh = wqh + tsz / 2;
        f16* wvh = wkh + tsz / 2;
        cvt_kernel<<<20480, 256, 0, stream>>>(x, wq, wk, wv, xh, wqh, wkh, wvh);
        // wqh/wkh/wvh are contiguous -> one stacked-W GEMM, N = 6144
        proj256_kernel<<<768, 512, 0, stream>>>(xh, wqh, cs, sn, qh, kh, vt);
    } else {
        proj_kernel<<<dim3(32, 16, 3), 256, 0, stream>>>(x, wq, wk, wv, qh, kh, vt);
        rope_kernel<<<dim3(16384, 2), 256, 0, stream>>>(qh, kh, cs, sn);
    }
    attn_kernel<<<256, 256, 0, stream>>>(qh, kh, vt, out);
}

// Round 3
// 322.271 us; speedup vs baseline: 1.5322x; 1.5322x over previous
//
#include <hip/hip_runtime.h>

#define Bc 2
#define Sc 2048
#define Dc 2048
#define Hc 16
#define DHc 128

typedef _Float16 f16;
typedef __attribute__((ext_vector_type(4))) _Float16 v4h;
typedef __attribute__((ext_vector_type(8))) _Float16 v8h;
typedef __attribute__((ext_vector_type(4))) float v4f;
typedef __attribute__((ext_vector_type(16))) float v16f;
typedef __attribute__((ext_vector_type(4))) float f32x4;

// ---------------------------------------------------------------------------
// Convert f32 inputs -> f16 once.
// ---------------------------------------------------------------------------
__global__ void cvt_kernel(const float* __restrict__ x, const float* __restrict__ wq,
                           const float* __restrict__ wk, const float* __restrict__ wv,
                           f16* __restrict__ xh, f16* __restrict__ wqh,
                           f16* __restrict__ wkh, f16* __restrict__ wvh)
{
    int bid = blockIdx.x;
    const float* src; f16* dst; int idx;
    if (bid < 8192)       { src = x;  dst = xh;  idx = bid; }
    else if (bid < 12288) { src = wq; dst = wqh; idx = bid - 8192; }
    else if (bid < 16384) { src = wk; dst = wkh; idx = bid - 12288; }
    else                  { src = wv; dst = wvh; idx = bid - 16384; }
    int i = idx * 256 + threadIdx.x;
    f32x4 v = ((const f32x4*)src)[i];
    v4h hv; hv[0]=(f16)v[0]; hv[1]=(f16)v[1]; hv[2]=(f16)v[2]; hv[3]=(f16)v[3];
    ((v4h*)dst)[i] = hv;
}

// ---------------------------------------------------------------------------
// Fused QKV projection GEMM C[4096][6144] = X . [wq;wk;wv]^T.
// 128x256 tile, BK=64, 8 waves, 768 blocks (3 balanced rounds), T2 swizzle.
// Round 3: counted-vmcnt pipeline with BOUNDED LIVENESS (r2 spilled: 4 frag
// sets = 128 VGPR live across asm walls -> 330 MB scratch traffic).
//   * 3 LDS buffers (144 KB); STAGE(t+2) issued at iter top -> the wait for
//     tile t is vmcnt(12): tile-t loads are TWO iterations old (HBM covered).
//   * raw s_barrier (no vmcnt(0) drain mid-loop); lgkmcnt(0) only before the
//     WAR barrier where it is free (MFMAs already consumed the frags).
//   * ONE fragment set; compiler inserts fine-grained lgkmcnt between
//     ds_read and MFMA (near-optimal per m97); hiding comes from the 2-iter
//     load flight + 2 waves/SIMD, not duplicated registers.
// ---------------------------------------------------------------------------
__launch_bounds__(512, 2)
__global__ void proj256_kernel(const f16* __restrict__ xh, const f16* __restrict__ wall,
                               const float* __restrict__ cs, const float* __restrict__ sn,
                               f16* __restrict__ qh, f16* __restrict__ kh,
                               f16* __restrict__ vt)
{
    const int bid = blockIdx.x;
    const int swz = (bid & 7) * 96 + (bid >> 3);     // 768 % 8 == 0 -> bijective
    const int mt = swz & 31, nt = swz >> 5;
    const int m0 = mt * 128, n0 = nt * 256;

    const int tid = threadIdx.x;
    const int wid = tid >> 6, lane = tid & 63;
    const int wr = wid >> 2, wc = wid & 3;           // 2 x 4 waves
    const int l15 = lane & 15, quad = lane >> 4;
    const int x7 = l15 & 7;

    // LDS: 3 buffers x (A 128x64 + B 256x64) halves = 147456 B
    __shared__ __align__(16) f16 lds[73728];

    const f16* aS[2]; const f16* bS[4];
    #pragma unroll
    for (int j = 0; j < 2; ++j) {
        int c = tid + j * 512;
        int r = c >> 3, s = c & 7;
        aS[j] = xh + (size_t)(m0 + r) * Dc + ((s ^ (r & 7)) * 8);
    }
    #pragma unroll
    for (int j = 0; j < 4; ++j) {
        int c = tid + j * 512;
        int r = c >> 3, s = c & 7;
        bS[j] = wall + (size_t)(n0 + r) * Dc + ((s ^ (r & 7)) * 8);
    }

#define STAGE(kt_, buf_) do {                                                   \
        const int _ko = (kt_) * 64;                                             \
        f16* _b = lds + (buf_) * 24576;                                         \
        _Pragma("unroll")                                                       \
        for (int j = 0; j < 2; ++j)                                             \
            __builtin_amdgcn_global_load_lds(                                   \
                (const __attribute__((address_space(1))) void*)(aS[j] + _ko),   \
                (__attribute__((address_space(3))) void*)(_b + j * 4096 + wid * 512), \
                16, 0, 0);                                                      \
        _Pragma("unroll")                                                       \
        for (int j = 0; j < 4; ++j)                                             \
            __builtin_amdgcn_global_load_lds(                                   \
                (const __attribute__((address_space(1))) void*)(bS[j] + _ko),   \
                (__attribute__((address_space(3))) void*)(_b + 8192 + j * 4096 + wid * 512), \
                16, 0, 0);                                                      \
    } while (0)

#define VMW12 asm volatile("s_waitcnt vmcnt(12)" ::: "memory")
#define VMW6  asm volatile("s_waitcnt vmcnt(6)"  ::: "memory")
#define VMW0  asm volatile("s_waitcnt vmcnt(0)"  ::: "memory")
#define LGKM0 asm volatile("s_waitcnt lgkmcnt(0)" ::: "memory")
#define BAR   __builtin_amdgcn_s_barrier()

    v4f acc[4][4];
    #pragma unroll
    for (int i = 0; i < 4; ++i)
        #pragma unroll
        for (int j = 0; j < 4; ++j)
            acc[i][j] = (v4f){0.f, 0.f, 0.f, 0.f};

    // prologue: 2 tiles in flight before first wait
    STAGE(0, 0);
    STAGE(1, 1);

    int bR = 0;      // buffer holding tile t
    int bSt = 2;     // buffer receiving tile t+2

    #pragma unroll 1
    for (int t = 0; t < 32; ++t) {
        if (t + 2 < 32) { STAGE(t + 2, bSt); VMW12; }
        else if (t + 1 < 32) { VMW6; }
        else { VMW0; }
        BAR;                          // tile t resident for ALL waves

        {   // single frag set, compiler-scheduled lgkm waits
            const f16* _Ab = lds + bR * 24576;
            const f16* _Bb = _Ab + 8192;
            v8h af[2][4], bf[2][4];
            #pragma unroll
            for (int kk = 0; kk < 2; ++kk) {
                #pragma unroll
                for (int mi = 0; mi < 4; ++mi)
                    af[kk][mi] = *(const v8h*)(_Ab + (wr * 64 + mi * 16 + l15) * 64
                                               + (((kk * 4 + quad) ^ x7) * 8));
                #pragma unroll
                for (int ni = 0; ni < 4; ++ni)
                    bf[kk][ni] = *(const v8h*)(_Bb + (wc * 64 + ni * 16 + l15) * 64
                                               + (((kk * 4 + quad) ^ x7) * 8));
            }
            __builtin_amdgcn_s_setprio(1);
            #pragma unroll
            for (int kk = 0; kk < 2; ++kk)
                #pragma unroll
                for (int mi = 0; mi < 4; ++mi)
                    #pragma unroll
                    for (int ni = 0; ni < 4; ++ni)
                        acc[mi][ni] = __builtin_amdgcn_mfma_f32_16x16x32_f16(
                            af[kk][mi], bf[kk][ni], acc[mi][ni], 0, 0, 0);
            __builtin_amdgcn_s_setprio(0);
        }

        LGKM0;                        // frag reads retired (already consumed)
        BAR;                          // buf[t%3] may now be overwritten (t+1's STAGE)

        bR  = (bR  == 2) ? 0 : bR  + 1;
        bSt = (bSt == 2) ? 0 : bSt + 1;
    }

#undef STAGE
#undef VMW12
#undef VMW6
#undef VMW0
#undef LGKM0
#undef BAR

    // ---------------- epilogue (z uniform per block: BN=256 | 2048) ---------
    const int z = n0 >> 11;
    const int bb = m0 >> 11, s0 = m0 & 2047;

    if (z < 2) {
        f16 (*Ep)[264] = (f16(*)[264])lds;
        #pragma unroll
        for (int mi = 0; mi < 4; ++mi)
            #pragma unroll
            for (int ni = 0; ni < 4; ++ni)
                #pragma unroll
                for (int r = 0; r < 4; ++r)
                    Ep[wr * 64 + mi * 16 + quad * 4 + r][wc * 64 + ni * 16 + l15] =
                        (f16)acc[mi][ni][r];
        __syncthreads();
        f16* outp = (z == 0) ? qh : kh;
        const float scl = (z == 0) ? 0.08838834764831845f : 1.0f;
        #pragma unroll
        for (int it = 0; it < 8; ++it) {
            int ch = tid + it * 512, row = ch >> 5, c = ch & 31;
            v8h val = *(const v8h*)&Ep[row][c * 8];
            int s = s0 + row;
            int nn = (n0 & 2047) + c * 8;
            int h = nn >> 7, d0 = nn & 127;
            const float* cp = cs + (size_t)s * DHc + d0;
            const float* sp = sn + (size_t)s * DHc + d0;
            f32x4 ca = *(const f32x4*)cp, cb = *(const f32x4*)(cp + 4);
            f32x4 sa = *(const f32x4*)sp, sb = *(const f32x4*)(sp + 4);
            float v[8];
            #pragma unroll
            for (int j = 0; j < 8; ++j) v[j] = (float)val[j];
            v8h rv;
            rv[0] = (f16)((v[0]*ca[0] - v[1]*sa[0]) * scl);
            rv[1] = (f16)((v[1]*ca[1] + v[0]*sa[1]) * scl);
            rv[2] = (f16)((v[2]*ca[2] - v[3]*sa[2]) * scl);
            rv[3] = (f16)((v[3]*ca[3] + v[2]*sa[3]) * scl);
            rv[4] = (f16)((v[4]*cb[0] - v[5]*sb[0]) * scl);
            rv[5] = (f16)((v[5]*cb[1] + v[4]*sb[1]) * scl);
            rv[6] = (f16)((v[6]*cb[2] - v[7]*sb[2]) * scl);
            rv[7] = (f16)((v[7]*cb[3] + v[6]*sb[3]) * scl);
            *(v8h*)(outp + ((size_t)(bb * Hc + h) * Sc + s) * DHc + d0) = rv;
        }
    } else {
        f16 (*Ep)[136] = (f16(*)[136])lds;
        #pragma unroll
        for (int mi = 0; mi < 4; ++mi)
            #pragma unroll
            for (int ni = 0; ni < 4; ++ni)
                #pragma unroll
                for (int r = 0; r < 4; ++r)
                    Ep[wc * 64 + ni * 16 + l15][wr * 64 + mi * 16 + quad * 4 + r] =
                        (f16)acc[mi][ni][r];
        __syncthreads();
        #pragma unroll
        for (int it = 0; it < 8; ++it) {
            int ch = tid + it * 512, n = ch >> 4, cm = ch & 15;
            int nn = (n0 & 2047) + n;
            int h = nn >> 7, d = nn & 127;
            int s = s0 + cm * 8;
            *(v8h*)(vt + ((size_t)(bb * Hc + h) * DHc + d) * Sc + s) =
                *(const v8h*)&Ep[n][cm * 8];
        }
    }
}

// ---------------------------------------------------------------------------
// Fallback proj (ws too small) + separate rope.
// ---------------------------------------------------------------------------
__launch_bounds__(256)
__global__ void proj_kernel(const float* __restrict__ x, const float* __restrict__ wq,
                            const float* __restrict__ wk, const float* __restrict__ wv,
                            f16* __restrict__ qh, f16* __restrict__ kh, f16* __restrict__ vt)
{
    const int z = blockIdx.z;
    const float* w = (z == 0) ? wq : ((z == 1) ? wk : wv);
    const int m0 = blockIdx.x * 128, n0 = blockIdx.y * 128;
    const int tid = threadIdx.x, lane = tid & 63, wid = tid >> 6;
    const int wm = wid >> 1, wn = wid & 1;
    const int l15 = lane & 15, quad = lane >> 4;

    __shared__ __align__(16) f16 smem[2 * 128 * 72];
    f16 (*As)[72] = (f16(*)[72])smem;
    f16 (*Bs)[72] = (f16(*)[72])(smem + 128 * 72);

    v4f acc[4][4];
    for (int i = 0; i < 4; ++i)
        for (int j = 0; j < 4; ++j)
            acc[i][j] = (v4f){0.f, 0.f, 0.f, 0.f};

    for (int k0 = 0; k0 < Dc; k0 += 64) {
        __syncthreads();
        for (int it = 0; it < 4; ++it) {
            int chunk = tid + it * 256;
            int r = chunk >> 3, cc = chunk & 7;
            const f32x4* pa = (const f32x4*)(x + (size_t)(m0 + r) * Dc + k0 + cc * 8);
            f32x4 a0 = pa[0], a1 = pa[1];
            v8h ha;
            ha[0]=(f16)a0[0]; ha[1]=(f16)a0[1]; ha[2]=(f16)a0[2]; ha[3]=(f16)a0[3];
            ha[4]=(f16)a1[0]; ha[5]=(f16)a1[1]; ha[6]=(f16)a1[2]; ha[7]=(f16)a1[3];
            *(v8h*)&As[r][cc * 8] = ha;
            const f32x4* pb = (const f32x4*)(w + (size_t)(n0 + r) * Dc + k0 + cc * 8);
            f32x4 b0 = pb[0], b1 = pb[1];
            v8h hb;
            hb[0]=(f16)b0[0]; hb[1]=(f16)b0[1]; hb[2]=(f16)b0[2]; hb[3]=(f16)b0[3];
            hb[4]=(f16)b1[0]; hb[5]=(f16)b1[1]; hb[6]=(f16)b1[2]; hb[7]=(f16)b1[3];
            *(v8h*)&Bs[r][cc * 8] = hb;
        }
        __syncthreads();
        for (int kk = 0; kk < 2; ++kk) {
            v8h af[4], bf[4];
            for (int mi = 0; mi < 4; ++mi)
                af[mi] = *(const v8h*)&As[wm * 64 + mi * 16 + l15][kk * 32 + quad * 8];
            for (int ni = 0; ni < 4; ++ni)
                bf[ni] = *(const v8h*)&Bs[wn * 64 + ni * 16 + l15][kk * 32 + quad * 8];
            for (int mi = 0; mi < 4; ++mi)
                for (int ni = 0; ni < 4; ++ni)
                    acc[mi][ni] = __builtin_amdgcn_mfma_f32_16x16x32_f16(
                        af[mi], bf[ni], acc[mi][ni], 0, 0, 0);
        }
    }
    __syncthreads();
    f16 (*Ep)[136] = (f16(*)[136])smem;
    for (int mi = 0; mi < 4; ++mi)
        for (int ni = 0; ni < 4; ++ni)
            for (int r = 0; r < 4; ++r) {
                int ml = wm * 64 + mi * 16 + quad * 4 + r;
                int nl = wn * 64 + ni * 16 + l15;
                f16 val = (f16)acc[mi][ni][r];
                if (z == 2) Ep[nl][ml] = val;
                else        Ep[ml][nl] = val;
            }
    __syncthreads();
    const int b = m0 >> 11, s0 = m0 & 2047, h = n0 >> 7;
    if (z < 2) {
        f16* outp = (z == 0) ? qh : kh;
        for (int it = 0; it < 8; ++it) {
            int ch = tid + it * 256, row = ch >> 4, c = ch & 15;
            *(v8h*)(outp + ((size_t)((b * Hc + h) * Sc) + s0 + row) * DHc + c * 8) =
                *(const v8h*)&Ep[row][c * 8];
        }
    } else {
        for (int it = 0; it < 8; ++it) {
            int ch = tid + it * 256, row = ch >> 4, c = ch & 15;
            *(v8h*)(vt + ((size_t)((b * Hc + h) * DHc) + row) * Sc + s0 + c * 8) =
                *(const v8h*)&Ep[row][c * 8];
        }
    }
}

__global__ void rope_kernel(f16* __restrict__ qh, f16* __restrict__ kh,
                            const float* __restrict__ cs, const float* __restrict__ sn)
{
    int i  = blockIdx.x * 256 + threadIdx.x;
    int d2 = i & 63;
    int s  = (i >> 6) & (Sc - 1);
    int bh = i >> 17;
    f16* t = blockIdx.y ? kh : qh;
    float scale = blockIdx.y ? 1.0f : 0.08838834764831845f;
    float c  = cs[s * DHc + 2 * d2];
    float sv = sn[s * DHc + 2 * d2];
    f16* p = t + ((size_t)bh * Sc + s) * DHc + 2 * d2;
    float t0 = (float)p[0], t1 = (float)p[1];
    p[0] = (f16)((t0 * c - t1 * sv) * scale);
    p[1] = (f16)((t1 * c + t0 * sv) * scale);
}

// ---------------------------------------------------------------------------
// Flash attention v6: balanced + XCD-local (unchanged this round).
// ---------------------------------------------------------------------------
__launch_bounds__(256, 2)
__global__ void attn_kernel(const f16* __restrict__ qh, const f16* __restrict__ kh,
                            const f16* __restrict__ vt, float* __restrict__ out)
{
    const int L = blockIdx.x;
    const int slot = L >> 3;
    const int bh = (L & 7) * 4 + (slot >> 3);
    const int p  = slot & 7;
    const int b = bh >> 4, h = bh & 15;
    const int tid = threadIdx.x, lane = tid & 63, w = tid >> 6;
    const int l31 = lane & 31, half = lane >> 5;
    const int sw = l31 & 7;

    __shared__ __align__(16) f16 smem[32768];     // K dbuf 32KB + V dbuf 32KB
    f16* ksm = smem;
    f16* vsm = smem + 16384;

    const size_t bhoff = (size_t)bh * Sc * DHc;

    const f16* ksrc[4]; const f16* vsrc[4];
    f16* kdst[4]; f16* vdst[4];
    #pragma unroll
    for (int j = 0; j < 4; ++j) {
        int slot0 = j * 256 + w * 64;
        {   int r = (slot0 >> 4) + (lane >> 4);
            int c = (lane & 15) ^ (r & 7);
            ksrc[j] = kh + bhoff + (size_t)r * DHc + c * 8;
            kdst[j] = ksm + slot0 * 8; }
        {   int r = (slot0 >> 3) + (lane >> 3);
            int c = (lane & 7) ^ (r & 7);
            vsrc[j] = vt + bhoff + (size_t)r * Sc + c * 8;
            vdst[j] = vsm + slot0 * 8; }
    }

#define STAGE(kt_, buf_) do {                                                   \
        int _ko = (kt_) * 64 * DHc;                                             \
        int _vo = (kt_) * 64;                                                   \
        int _lb = (buf_) * 8192;                                                \
        _Pragma("unroll")                                                       \
        for (int j = 0; j < 4; ++j) {                                           \
            __builtin_amdgcn_global_load_lds(                                   \
                (const __attribute__((address_space(1))) void*)(ksrc[j] + _ko), \
                (__attribute__((address_space(3))) void*)(kdst[j] + _lb), 16, 0, 0); \
            __builtin_amdgcn_global_load_lds(                                   \
                (const __attribute__((address_space(1))) void*)(vsrc[j] + _vo), \
                (__attribute__((address_space(3))) void*)(vdst[j] + _lb), 16, 0, 0); \
        } } while (0)

    const int qtA = 15 - p;
    const int nktA = 2 * qtA + 2;     // + nktB = 34 for every block

    int ibuf = 0;
    STAGE(0, 0);

    #pragma unroll 1
    for (int ph = 0; ph < 2; ++ph) {
        const int qt  = ph ? p : qtA;
        const int nkt = 2 * qt + 2;
        const int q0  = qt * 128 + w * 32;
        const int qg  = q0 + l31;

        v8h qf[8];
        const f16* qrow = qh + bhoff + (size_t)qg * DHc;
        #pragma unroll
        for (int s = 0; s < 8; ++s)
            qf[s] = *(const v8h*)(qrow + s * 16 + half * 8);

        float l_run = 0.f;
        v16f o[4];
        #pragma unroll
        for (int i = 0; i < 4; ++i)
            #pragma unroll
            for (int r = 0; r < 16; ++r) o[i][r] = 0.f;

        #pragma unroll 1
        for (int kt = 0; kt < nkt; ++kt, ++ibuf) {
            __syncthreads();             // publishes buf[ibuf&1]
            const int buf = ibuf & 1;
            const int ni = ibuf + 1;
            if (ni < 34) {
                int tn = (ni < nktA) ? ni : ni - nktA;
                STAGE(tn, ni & 1);
            }
            if (q0 + 31 < kt * 64) continue;   // fully masked; barriers uniform

            const f16* kbuf = ksm + buf * 8192;
            const f16* vbuf = vsm + buf * 8192;
            const bool do1 = (kt * 64 + 32 <= q0 + 31);

            v16f st0, st1;
            #pragma unroll
            for (int r = 0; r < 16; ++r) { st0[r] = 0.f; st1[r] = 0.f; }
            #pragma unroll
            for (int s = 0; s < 8; ++s) {
                int c = ((s * 2 + half) ^ sw) * 8;
                v8h kf0 = *(const v8h*)(kbuf + l31 * 128 + c);
                st0 = __builtin_amdgcn_mfma_f32_32x32x16_f16(kf0, qf[s], st0, 0, 0, 0);
                if (do1) {
                    v8h kf1 = *(const v8h*)(kbuf + (32 + l31) * 128 + c);
                    st1 = __builtin_amdgcn_mfma_f32_32x32x16_f16(kf1, qf[s], st1, 0, 0, 0);
                }
            }

            float sum = 0.f;
            #pragma unroll
            for (int r = 0; r < 16; ++r) {
                int key = kt * 64 + (r & 3) + 8 * (r >> 2) + 4 * half;
                float sv = (key > qg) ? -1e30f : st0[r];
                float pe = __expf(sv);
                st0[r] = pe; sum += pe;
            }
            if (do1) {
                #pragma unroll
                for (int r = 0; r < 16; ++r) {
                    int key = kt * 64 + 32 + (r & 3) + 8 * (r >> 2) + 4 * half;
                    float sv = (key > qg) ? -1e30f : st1[r];
                    float pe = __expf(sv);
                    st1[r] = pe; sum += pe;
                }
            }
            sum += __shfl_xor(sum, 32);
            l_run += sum;

            #pragma unroll
            for (int s2 = 0; s2 < 4; ++s2) {
                v4h bfr;
                bfr[0]=(f16)st0[4*s2]; bfr[1]=(f16)st0[4*s2+1];
                bfr[2]=(f16)st0[4*s2+2]; bfr[3]=(f16)st0[4*s2+3];
                int c = ((s2 ^ sw) * 8) + half * 4;
                #pragma unroll
                for (int dt = 0; dt < 4; ++dt) {
                    v4h vf = *(const v4h*)(vbuf + (dt * 32 + l31) * 64 + c);
                    o[dt] = __builtin_amdgcn_mfma_f32_32x32x8f16(vf, bfr, o[dt], 0, 0, 0);
                }
            }
            if (do1) {
                #pragma unroll
                for (int s2 = 0; s2 < 4; ++s2) {
                    v4h bfr;
                    bfr[0]=(f16)st1[4*s2]; bfr[1]=(f16)st1[4*s2+1];
                    bfr[2]=(f16)st1[4*s2+2]; bfr[3]=(f16)st1[4*s2+3];
                    int c = (((4 + s2) ^ sw) * 8) + half * 4;
                    #pragma unroll
                    for (int dt = 0; dt < 4; ++dt) {
                        v4h vf = *(const v4h*)(vbuf + (dt * 32 + l31) * 64 + c);
                        o[dt] = __builtin_amdgcn_mfma_f32_32x32x8f16(vf, bfr, o[dt], 0, 0, 0);
                    }
                }
            }
        }

        float inv = 1.f / l_run;
        float mxd = -1e30f;
        #pragma unroll
        for (int dt = 0; dt < 4; ++dt)
            #pragma unroll
            for (int r = 0; r < 16; ++r) {
                o[dt][r] *= inv;
                mxd = fmaxf(mxd, o[dt][r]);
            }
        mxd = fmaxf(mxd, __shfl_xor(mxd, 32));
        float sd = 0.f;
        #pragma unroll
        for (int dt = 0; dt < 4; ++dt)
            #pragma unroll
            for (int r = 0; r < 16; ++r) {
                float t = __expf(o[dt][r] - mxd);
                o[dt][r] = t;
                sd += t;
            }
        sd += __shfl_xor(sd, 32);
        float rinv = 1.f / sd;

        float* orow = out + (size_t)(b * Sc + qg) * Dc + h * DHc;
        #pragma unroll
        for (int dt = 0; dt < 4; ++dt)
            #pragma unroll
            for (int g = 0; g < 4; ++g) {
                f32x4 vv;
                vv[0] = o[dt][4*g+0] * rinv;
                vv[1] = o[dt][4*g+1] * rinv;
                vv[2] = o[dt][4*g+2] * rinv;
                vv[3] = o[dt][4*g+3] * rinv;
                *(f32x4*)(orow + dt * 32 + g * 8 + half * 4) = vv;
            }
    }
#undef STAGE
}

extern "C" void kernel_launch(void* const* d_in, const int* in_sizes, int n_in,
                              void* d_out, int out_size, void* d_ws, size_t ws_size,
                              hipStream_t stream)
{
    const float* x  = (const float*)d_in[0];
    const float* wq = (const float*)d_in[1];
    const float* wk = (const float*)d_in[2];
    const float* wv = (const float*)d_in[3];
    const float* cs = (const float*)d_in[4];
    const float* sn = (const float*)d_in[5];
    float* out = (float*)d_out;

    const size_t tsz = (size_t)Bc * Hc * Sc * DHc;   // 8,388,608 halves
    f16* qh = (f16*)d_ws;
    f16* kh = qh + tsz;
    f16* vt = kh + tsz;

    if (ws_size >= 11 * tsz) {
        f16* xh  = vt + tsz;
        f16* wqh = xh + tsz;
        f16* wkh = wqh + tsz / 2;
        f16* wvh = wkh + tsz / 2;
        cvt_kernel<<<20480, 256, 0, stream>>>(x, wq, wk, wv, xh, wqh, wkh, wvh);
        // wqh/wkh/wvh are contiguous -> one stacked-W GEMM, N = 6144
        proj256_kernel<<<768, 512, 0, stream>>>(xh, wqh, cs, sn, qh, kh, vt);
    } else {
        proj_kernel<<<dim3(32, 16, 3), 256, 0, stream>>>(x, wq, wk, wv, qh, kh, vt);
        rope_kernel<<<dim3(16384, 2), 256, 0, stream>>>(qh, kh, cs, sn);
    }
    attn_kernel<<<256, 256, 0, stream>>>(qh, kh, vt, out);
}

// Round 5
// 320.637 us; speedup vs baseline: 1.5400x; 1.0051x over previous
//
#include <hip/hip_runtime.h>

#define Bc 2
#define Sc 2048
#define Dc 2048
#define Hc 16
#define DHc 128

typedef _Float16 f16;
typedef __attribute__((ext_vector_type(4))) _Float16 v4h;
typedef __attribute__((ext_vector_type(8))) _Float16 v8h;
typedef __attribute__((ext_vector_type(4))) float v4f;
typedef __attribute__((ext_vector_type(16))) float v16f;
typedef __attribute__((ext_vector_type(4))) float f32x4;

// ---------------------------------------------------------------------------
// Convert f32 inputs -> f16 once.
// ---------------------------------------------------------------------------
__global__ void cvt_kernel(const float* __restrict__ x, const float* __restrict__ wq,
                           const float* __restrict__ wk, const float* __restrict__ wv,
                           f16* __restrict__ xh, f16* __restrict__ wqh,
                           f16* __restrict__ wkh, f16* __restrict__ wvh)
{
    int bid = blockIdx.x;
    const float* src; f16* dst; int idx;
    if (bid < 8192)       { src = x;  dst = xh;  idx = bid; }
    else if (bid < 12288) { src = wq; dst = wqh; idx = bid - 8192; }
    else if (bid < 16384) { src = wk; dst = wkh; idx = bid - 12288; }
    else                  { src = wv; dst = wvh; idx = bid - 16384; }
    int i = idx * 256 + threadIdx.x;
    f32x4 v = ((const f32x4*)src)[i];
    v4h hv; hv[0]=(f16)v[0]; hv[1]=(f16)v[1]; hv[2]=(f16)v[2]; hv[3]=(f16)v[3];
    ((v4h*)dst)[i] = hv;
}

// ---------------------------------------------------------------------------
// Fused QKV projection GEMM C[4096][6144] = X . [wq;wk;wv]^T.
// 128x256 tile, BK=64, 8 waves, 768 blocks (3 exact rounds), T2 swizzle.
// 2 phases per K-tile (m201-style): per phase {8 ds_read issue + 3 staged
// gloads + s_barrier + 16 MFMA + s_barrier}. Each wave's lgkm-wait clears
// while the LDS queue serves other waves' reads -> MFMA || LDS.
// Counted vmcnt(6) once per K-tile (tile t+1, staged ~2 iters earlier).
// 3-buffer ring: STAGE target is always 2 mod 3 from the buffer being read.
// ---------------------------------------------------------------------------
__launch_bounds__(512, 2)
__global__ void proj256_kernel(const f16* __restrict__ xh, const f16* __restrict__ wall,
                               const float* __restrict__ cs, const float* __restrict__ sn,
                               f16* __restrict__ qh, f16* __restrict__ kh,
                               f16* __restrict__ vt)
{
    const int bid = blockIdx.x;
    const int swz = (bid & 7) * 96 + (bid >> 3);     // 768 % 8 == 0 -> bijective
    const int mt = swz & 31, nt = swz >> 5;
    const int m0 = mt * 128, n0 = nt * 256;

    const int tid = threadIdx.x;
    const int wid = tid >> 6, lane = tid & 63;
    const int wr = wid >> 2, wc = wid & 3;           // 2 x 4 waves
    const int l15 = lane & 15, quad = lane >> 4;
    const int x7 = l15 & 7;

    // LDS: 3 buffers x (A 128x64 + B 256x64) halves = 147456 B
    __shared__ __align__(16) f16 lds[73728];

    const f16* aS[2]; const f16* bS[4];
    #pragma unroll
    for (int j = 0; j < 2; ++j) {
        int c = tid + j * 512;
        int r = c >> 3, s = c & 7;
        aS[j] = xh + (size_t)(m0 + r) * Dc + ((s ^ (r & 7)) * 8);
    }
    #pragma unroll
    for (int j = 0; j < 4; ++j) {
        int c = tid + j * 512;
        int r = c >> 3, s = c & 7;
        bS[j] = wall + (size_t)(n0 + r) * Dc + ((s ^ (r & 7)) * 8);
    }

#define GLD(src_, dst_)                                                         \
    __builtin_amdgcn_global_load_lds(                                           \
        (const __attribute__((address_space(1))) void*)(src_),                  \
        (__attribute__((address_space(3))) void*)(dst_), 16, 0, 0)

#define STAGE_P0(kt_, buf_) do {                                                \
        const int _ko = (kt_) * 64;                                             \
        f16* _b = lds + (buf_) * 24576;                                         \
        GLD(aS[0] + _ko, _b + wid * 512);                                       \
        GLD(aS[1] + _ko, _b + 4096 + wid * 512);                                \
        GLD(bS[0] + _ko, _b + 8192 + wid * 512);                                \
    } while (0)

#define STAGE_P1(kt_, buf_) do {                                                \
        const int _ko = (kt_) * 64;                                             \
        f16* _b = lds + (buf_) * 24576;                                         \
        GLD(bS[1] + _ko, _b + 8192 + 4096  + wid * 512);                        \
        GLD(bS[2] + _ko, _b + 8192 + 8192  + wid * 512);                        \
        GLD(bS[3] + _ko, _b + 8192 + 12288 + wid * 512);                        \
    } while (0)

#define VMW6  asm volatile("s_waitcnt vmcnt(6)"  ::: "memory")
#define VMW0  asm volatile("s_waitcnt vmcnt(0)"  ::: "memory")
#define LGKM0 asm volatile("s_waitcnt lgkmcnt(0)" ::: "memory")
#define BAR   __builtin_amdgcn_s_barrier()

#define PHASE(kk_, bR_) do {                                                    \
        const f16* _Ab = lds + (bR_) * 24576;                                   \
        const f16* _Bb = _Ab + 8192;                                            \
        v8h af[4], bf[4];                                                       \
        _Pragma("unroll")                                                       \
        for (int mi = 0; mi < 4; ++mi)                                          \
            af[mi] = *(const v8h*)(_Ab + (wr * 64 + mi * 16 + l15) * 64         \
                                   + ((((kk_) * 4 + quad) ^ x7) * 8));          \
        _Pragma("unroll")                                                       \
        for (int ni = 0; ni < 4; ++ni)                                          \
            bf[ni] = *(const v8h*)(_Bb + (wc * 64 + ni * 16 + l15) * 64         \
                                   + ((((kk_) * 4 + quad) ^ x7) * 8));          \
        PH_TAIL;                                                                \
        __builtin_amdgcn_s_setprio(1);                                          \
        _Pragma("unroll")                                                       \
        for (int mi = 0; mi < 4; ++mi)                                          \
            _Pragma("unroll")                                                   \
            for (int ni = 0; ni < 4; ++ni)                                      \
                acc[mi][ni] = __builtin_amdgcn_mfma_f32_16x16x32_f16(           \
                    af[mi], bf[ni], acc[mi][ni], 0, 0, 0);                      \
        __builtin_amdgcn_s_setprio(0);                                          \
    } while (0)

    v4f acc[4][4];
    #pragma unroll
    for (int i = 0; i < 4; ++i)
        #pragma unroll
        for (int j = 0; j < 4; ++j)
            acc[i][j] = (v4f){0.f, 0.f, 0.f, 0.f};

    // prologue: tiles 0,1 fully staged; wait tile 0 (all but newest 6)
    STAGE_P0(0, 0); STAGE_P1(0, 0);
    STAGE_P0(1, 1); STAGE_P1(1, 1);
    VMW6;
    BAR;

    int bR = 0;      // buffer holding tile t
    int bSt = 2;     // buffer receiving tile t+2

    #pragma unroll 1
    for (int t = 0; t < 32; ++t) {
        // ---- phase 0: frags kk=0 + 3 staged loads ----
        {
#define PH_TAIL do { if (t + 2 < 32) STAGE_P0(t + 2, bSt); BAR; } while (0)
            PHASE(0, bR);
#undef PH_TAIL
        }
        BAR;
        // ---- phase 1: frags kk=1 + 3 staged loads + counted wait ----
        {
#define PH_TAIL do { if (t + 2 < 32) STAGE_P1(t + 2, bSt);                      \
                     if (t < 30) { VMW6; } else { VMW0; }                       \
                     BAR; } while (0)
            PHASE(1, bR);
#undef PH_TAIL
        }
        LGKM0;
        BAR;             // all reads of bR retired; next iter may overwrite it

        bR  = (bR  == 2) ? 0 : bR  + 1;
        bSt = (bSt == 2) ? 0 : bSt + 1;
    }

#undef STAGE_P0
#undef STAGE_P1
#undef GLD
#undef VMW6
#undef VMW0
#undef LGKM0
#undef BAR
#undef PHASE

    // ---------------- epilogue (z uniform per block: BN=256 | 2048) ---------
    const int z = n0 >> 11;
    const int bb = m0 >> 11, s0 = m0 & 2047;

    if (z < 2) {
        f16 (*Ep)[264] = (f16(*)[264])lds;
        #pragma unroll
        for (int mi = 0; mi < 4; ++mi)
            #pragma unroll
            for (int ni = 0; ni < 4; ++ni)
                #pragma unroll
                for (int r = 0; r < 4; ++r)
                    Ep[wr * 64 + mi * 16 + quad * 4 + r][wc * 64 + ni * 16 + l15] =
                        (f16)acc[mi][ni][r];
        __syncthreads();
        f16* outp = (z == 0) ? qh : kh;
        const float scl = (z == 0) ? 0.08838834764831845f : 1.0f;
        #pragma unroll
        for (int it = 0; it < 8; ++it) {
            int ch = tid + it * 512, row = ch >> 5, c = ch & 31;
            v8h val = *(const v8h*)&Ep[row][c * 8];
            int s = s0 + row;
            int nn = (n0 & 2047) + c * 8;
            int h = nn >> 7, d0 = nn & 127;
            const float* cp = cs + (size_t)s * DHc + d0;
            const float* sp = sn + (size_t)s * DHc + d0;
            f32x4 ca = *(const f32x4*)cp, cb = *(const f32x4*)(cp + 4);
            f32x4 sa = *(const f32x4*)sp, sb = *(const f32x4*)(sp + 4);
            float v[8];
            #pragma unroll
            for (int j = 0; j < 8; ++j) v[j] = (float)val[j];
            v8h rv;
            rv[0] = (f16)((v[0]*ca[0] - v[1]*sa[0]) * scl);
            rv[1] = (f16)((v[1]*ca[1] + v[0]*sa[1]) * scl);
            rv[2] = (f16)((v[2]*ca[2] - v[3]*sa[2]) * scl);
            rv[3] = (f16)((v[3]*ca[3] + v[2]*sa[3]) * scl);
            rv[4] = (f16)((v[4]*cb[0] - v[5]*sb[0]) * scl);
            rv[5] = (f16)((v[5]*cb[1] + v[4]*sb[1]) * scl);
            rv[6] = (f16)((v[6]*cb[2] - v[7]*sb[2]) * scl);
            rv[7] = (f16)((v[7]*cb[3] + v[6]*sb[3]) * scl);
            *(v8h*)(outp + ((size_t)(bb * Hc + h) * Sc + s) * DHc + d0) = rv;
        }
    } else {
        f16 (*Ep)[136] = (f16(*)[136])lds;
        #pragma unroll
        for (int mi = 0; mi < 4; ++mi)
            #pragma unroll
            for (int ni = 0; ni < 4; ++ni)
                #pragma unroll
                for (int r = 0; r < 4; ++r)
                    Ep[wc * 64 + ni * 16 + l15][wr * 64 + mi * 16 + quad * 4 + r] =
                        (f16)acc[mi][ni][r];
        __syncthreads();
        #pragma unroll
        for (int it = 0; it < 8; ++it) {
            int ch = tid + it * 512, n = ch >> 4, cm = ch & 15;
            int nn = (n0 & 2047) + n;
            int h = nn >> 7, d = nn & 127;
            int s = s0 + cm * 8;
            *(v8h*)(vt + ((size_t)(bb * Hc + h) * DHc + d) * Sc + s) =
                *(const v8h*)&Ep[n][cm * 8];
        }
    }
}

// ---------------------------------------------------------------------------
// Fallback proj (ws too small) + separate rope.
// ---------------------------------------------------------------------------
__launch_bounds__(256)
__global__ void proj_kernel(const float* __restrict__ x, const float* __restrict__ wq,
                            const float* __restrict__ wk, const float* __restrict__ wv,
                            f16* __restrict__ qh, f16* __restrict__ kh, f16* __restrict__ vt)
{
    const int z = blockIdx.z;
    const float* w = (z == 0) ? wq : ((z == 1) ? wk : wv);
    const int m0 = blockIdx.x * 128, n0 = blockIdx.y * 128;
    const int tid = threadIdx.x, lane = tid & 63, wid = tid >> 6;
    const int wm = wid >> 1, wn = wid & 1;
    const int l15 = lane & 15, quad = lane >> 4;

    __shared__ __align__(16) f16 smem[2 * 128 * 72];
    f16 (*As)[72] = (f16(*)[72])smem;
    f16 (*Bs)[72] = (f16(*)[72])(smem + 128 * 72);

    v4f acc[4][4];
    for (int i = 0; i < 4; ++i)
        for (int j = 0; j < 4; ++j)
            acc[i][j] = (v4f){0.f, 0.f, 0.f, 0.f};

    for (int k0 = 0; k0 < Dc; k0 += 64) {
        __syncthreads();
        for (int it = 0; it < 4; ++it) {
            int chunk = tid + it * 256;
            int r = chunk >> 3, cc = chunk & 7;
            const f32x4* pa = (const f32x4*)(x + (size_t)(m0 + r) * Dc + k0 + cc * 8);
            f32x4 a0 = pa[0], a1 = pa[1];
            v8h ha;
            ha[0]=(f16)a0[0]; ha[1]=(f16)a0[1]; ha[2]=(f16)a0[2]; ha[3]=(f16)a0[3];
            ha[4]=(f16)a1[0]; ha[5]=(f16)a1[1]; ha[6]=(f16)a1[2]; ha[7]=(f16)a1[3];
            *(v8h*)&As[r][cc * 8] = ha;
            const f32x4* pb = (const f32x4*)(w + (size_t)(n0 + r) * Dc + k0 + cc * 8);
            f32x4 b0 = pb[0], b1 = pb[1];
            v8h hb;
            hb[0]=(f16)b0[0]; hb[1]=(f16)b0[1]; hb[2]=(f16)b0[2]; hb[3]=(f16)b0[3];
            hb[4]=(f16)b1[0]; hb[5]=(f16)b1[1]; hb[6]=(f16)b1[2]; hb[7]=(f16)b1[3];
            *(v8h*)&Bs[r][cc * 8] = hb;
        }
        __syncthreads();
        for (int kk = 0; kk < 2; ++kk) {
            v8h af[4], bf[4];
            for (int mi = 0; mi < 4; ++mi)
                af[mi] = *(const v8h*)&As[wm * 64 + mi * 16 + l15][kk * 32 + quad * 8];
            for (int ni = 0; ni < 4; ++ni)
                bf[ni] = *(const v8h*)&Bs[wn * 64 + ni * 16 + l15][kk * 32 + quad * 8];
            for (int mi = 0; mi < 4; ++mi)
                for (int ni = 0; ni < 4; ++ni)
                    acc[mi][ni] = __builtin_amdgcn_mfma_f32_16x16x32_f16(
                        af[mi], bf[ni], acc[mi][ni], 0, 0, 0);
        }
    }
    __syncthreads();
    f16 (*Ep)[136] = (f16(*)[136])smem;
    for (int mi = 0; mi < 4; ++mi)
        for (int ni = 0; ni < 4; ++ni)
            for (int r = 0; r < 4; ++r) {
                int ml = wm * 64 + mi * 16 + quad * 4 + r;
                int nl = wn * 64 + ni * 16 + l15;
                f16 val = (f16)acc[mi][ni][r];
                if (z == 2) Ep[nl][ml] = val;
                else        Ep[ml][nl] = val;
            }
    __syncthreads();
    const int b = m0 >> 11, s0 = m0 & 2047, h = n0 >> 7;
    if (z < 2) {
        f16* outp = (z == 0) ? qh : kh;
        for (int it = 0; it < 8; ++it) {
            int ch = tid + it * 256, row = ch >> 4, c = ch & 15;
            *(v8h*)(outp + ((size_t)((b * Hc + h) * Sc) + s0 + row) * DHc + c * 8) =
                *(const v8h*)&Ep[row][c * 8];
        }
    } else {
        for (int it = 0; it < 8; ++it) {
            int ch = tid + it * 256, row = ch >> 4, c = ch & 15;
            *(v8h*)(vt + ((size_t)((b * Hc + h) * DHc) + row) * Sc + s0 + c * 8) =
                *(const v8h*)&Ep[row][c * 8];
        }
    }
}

__global__ void rope_kernel(f16* __restrict__ qh, f16* __restrict__ kh,
                            const float* __restrict__ cs, const float* __restrict__ sn)
{
    int i  = blockIdx.x * 256 + threadIdx.x;
    int d2 = i & 63;
    int s  = (i >> 6) & (Sc - 1);
    int bh = i >> 17;
    f16* t = blockIdx.y ? kh : qh;
    float scale = blockIdx.y ? 1.0f : 0.08838834764831845f;
    float c  = cs[s * DHc + 2 * d2];
    float sv = sn[s * DHc + 2 * d2];
    f16* p = t + ((size_t)bh * Sc + s) * DHc + 2 * d2;
    float t0 = (float)p[0], t1 = (float)p[1];
    p[0] = (f16)((t0 * c - t1 * sv) * scale);
    p[1] = (f16)((t1 * c + t0 * sv) * scale);
}

// ---------------------------------------------------------------------------
// Flash attention v7: one q-tile per block, 512 blocks -> 2 blocks/CU
// (2 waves/SIMD; cross-block overlap replaces the missing TLP).
// Longest q-tiles launch first per XCD (LPT packing). XCD-local bh mapping
// (4 bh per XCD -> K+V 4 MB fits L2). Body identical to v6.
// ---------------------------------------------------------------------------
__launch_bounds__(256, 2)
__global__ void attn_kernel(const f16* __restrict__ qh, const f16* __restrict__ kh,
                            const f16* __restrict__ vt, float* __restrict__ out)
{
    const int L = blockIdx.x;
    const int s_ = L >> 3;
    const int bh = (L & 7) * 4 + (s_ >> 4);
    const int qt = 15 - (s_ & 15);               // descending work order
    const int b = bh >> 4, h = bh & 15;
    const int tid = threadIdx.x, lane = tid & 63, w = tid >> 6;
    const int l31 = lane & 31, half = lane >> 5;
    const int sw = l31 & 7;

    __shared__ __align__(16) f16 smem[32768];     // K dbuf 32KB + V dbuf 32KB
    f16* ksm = smem;
    f16* vsm = smem + 16384;

    const size_t bhoff = (size_t)bh * Sc * DHc;

    const f16* ksrc[4]; const f16* vsrc[4];
    f16* kdst[4]; f16* vdst[4];
    #pragma unroll
    for (int j = 0; j < 4; ++j) {
        int slot0 = j * 256 + w * 64;
        {   int r = (slot0 >> 4) + (lane >> 4);
            int c = (lane & 15) ^ (r & 7);
            ksrc[j] = kh + bhoff + (size_t)r * DHc + c * 8;
            kdst[j] = ksm + slot0 * 8; }
        {   int r = (slot0 >> 3) + (lane >> 3);
            int c = (lane & 7) ^ (r & 7);
            vsrc[j] = vt + bhoff + (size_t)r * Sc + c * 8;
            vdst[j] = vsm + slot0 * 8; }
    }

#define STAGE(kt_, buf_) do {                                                   \
        int _ko = (kt_) * 64 * DHc;                                             \
        int _vo = (kt_) * 64;                                                   \
        int _lb = (buf_) * 8192;                                                \
        _Pragma("unroll")                                                       \
        for (int j = 0; j < 4; ++j) {                                           \
            __builtin_amdgcn_global_load_lds(                                   \
                (const __attribute__((address_space(1))) void*)(ksrc[j] + _ko), \
                (__attribute__((address_space(3))) void*)(kdst[j] + _lb), 16, 0, 0); \
            __builtin_amdgcn_global_load_lds(                                   \
                (const __attribute__((address_space(1))) void*)(vsrc[j] + _vo), \
                (__attribute__((address_space(3))) void*)(vdst[j] + _lb), 16, 0, 0); \
        } } while (0)

    const int nkt = 2 * qt + 2;
    const int q0  = qt * 128 + w * 32;
    const int qg  = q0 + l31;

    v8h qf[8];
    const f16* qrow = qh + bhoff + (size_t)qg * DHc;
    #pragma unroll
    for (int s = 0; s < 8; ++s)
        qf[s] = *(const v8h*)(qrow + s * 16 + half * 8);

    float l_run = 0.f;
    v16f o[4];
    #pragma unroll
    for (int i = 0; i < 4; ++i)
        #pragma unroll
        for (int r = 0; r < 16; ++r) o[i][r] = 0.f;

    STAGE(0, 0);

    #pragma unroll 1
    for (int kt = 0; kt < nkt; ++kt) {
        __syncthreads();             // publishes buf[kt&1]
        if (kt + 1 < nkt) STAGE(kt + 1, (kt + 1) & 1);
        if (q0 + 31 < kt * 64) continue;   // fully masked; barriers uniform

        const f16* kbuf = ksm + (kt & 1) * 8192;
        const f16* vbuf = vsm + (kt & 1) * 8192;
        const bool do1 = (kt * 64 + 32 <= q0 + 31);

        v16f st0, st1;
        #pragma unroll
        for (int r = 0; r < 16; ++r) { st0[r] = 0.f; st1[r] = 0.f; }
        #pragma unroll
        for (int s = 0; s < 8; ++s) {
            int c = ((s * 2 + half) ^ sw) * 8;
            v8h kf0 = *(const v8h*)(kbuf + l31 * 128 + c);
            st0 = __builtin_amdgcn_mfma_f32_32x32x16_f16(kf0, qf[s], st0, 0, 0, 0);
            if (do1) {
                v8h kf1 = *(const v8h*)(kbuf + (32 + l31) * 128 + c);
                st1 = __builtin_amdgcn_mfma_f32_32x32x16_f16(kf1, qf[s], st1, 0, 0, 0);
            }
        }

        float sum = 0.f;
        #pragma unroll
        for (int r = 0; r < 16; ++r) {
            int key = kt * 64 + (r & 3) + 8 * (r >> 2) + 4 * half;
            float sv = (key > qg) ? -1e30f : st0[r];
            float pe = __expf(sv);
            st0[r] = pe; sum += pe;
        }
        if (do1) {
            #pragma unroll
            for (int r = 0; r < 16; ++r) {
                int key = kt * 64 + 32 + (r & 3) + 8 * (r >> 2) + 4 * half;
                float sv = (key > qg) ? -1e30f : st1[r];
                float pe = __expf(sv);
                st1[r] = pe; sum += pe;
            }
        }
        sum += __shfl_xor(sum, 32);
        l_run += sum;

        #pragma unroll
        for (int s2 = 0; s2 < 4; ++s2) {
            v4h bfr;
            bfr[0]=(f16)st0[4*s2]; bfr[1]=(f16)st0[4*s2+1];
            bfr[2]=(f16)st0[4*s2+2]; bfr[3]=(f16)st0[4*s2+3];
            int c = ((s2 ^ sw) * 8) + half * 4;
            #pragma unroll
            for (int dt = 0; dt < 4; ++dt) {
                v4h vf = *(const v4h*)(vbuf + (dt * 32 + l31) * 64 + c);
                o[dt] = __builtin_amdgcn_mfma_f32_32x32x8f16(vf, bfr, o[dt], 0, 0, 0);
            }
        }
        if (do1) {
            #pragma unroll
            for (int s2 = 0; s2 < 4; ++s2) {
                v4h bfr;
                bfr[0]=(f16)st1[4*s2]; bfr[1]=(f16)st1[4*s2+1];
                bfr[2]=(f16)st1[4*s2+2]; bfr[3]=(f16)st1[4*s2+3];
                int c = (((4 + s2) ^ sw) * 8) + half * 4;
                #pragma unroll
                for (int dt = 0; dt < 4; ++dt) {
                    v4h vf = *(const v4h*)(vbuf + (dt * 32 + l31) * 64 + c);
                    o[dt] = __builtin_amdgcn_mfma_f32_32x32x8f16(vf, bfr, o[dt], 0, 0, 0);
                }
            }
        }
    }

    // epilogue: normalize + softmax over Dh + paired-lane stores
    float inv = 1.f / l_run;
    float mxd = -1e30f;
    #pragma unroll
    for (int dt = 0; dt < 4; ++dt)
        #pragma unroll
        for (int r = 0; r < 16; ++r) {
            o[dt][r] *= inv;
            mxd = fmaxf(mxd, o[dt][r]);
        }
    mxd = fmaxf(mxd, __shfl_xor(mxd, 32));
    float sd = 0.f;
    #pragma unroll
    for (int dt = 0; dt < 4; ++dt)
        #pragma unroll
        for (int r = 0; r < 16; ++r) {
            float t = __expf(o[dt][r] - mxd);
            o[dt][r] = t;
            sd += t;
        }
    sd += __shfl_xor(sd, 32);
    float rinv = 1.f / sd;

    float* orow = out + (size_t)(b * Sc + qg) * Dc + h * DHc;
    #pragma unroll
    for (int dt = 0; dt < 4; ++dt)
        #pragma unroll
        for (int g = 0; g < 4; ++g) {
            f32x4 vv;
            vv[0] = o[dt][4*g+0] * rinv;
            vv[1] = o[dt][4*g+1] * rinv;
            vv[2] = o[dt][4*g+2] * rinv;
            vv[3] = o[dt][4*g+3] * rinv;
            *(f32x4*)(orow + dt * 32 + g * 8 + half * 4) = vv;
        }
#undef STAGE
}

extern "C" void kernel_launch(void* const* d_in, const int* in_sizes, int n_in,
                              void* d_out, int out_size, void* d_ws, size_t ws_size,
                              hipStream_t stream)
{
    const float* x  = (const float*)d_in[0];
    const float* wq = (const float*)d_in[1];
    const float* wk = (const float*)d_in[2];
    const float* wv = (const float*)d_in[3];
    const float* cs = (const float*)d_in[4];
    const float* sn = (const float*)d_in[5];
    float* out = (float*)d_out;

    const size_t tsz = (size_t)Bc * Hc * Sc * DHc;   // 8,388,608 halves
    f16* qh = (f16*)d_ws;
    f16* kh = qh + tsz;
    f16* vt = kh + tsz;

    if (ws_size >= 11 * tsz) {
        f16* xh  = vt + tsz;
        f16* wqh = xh + tsz;
        f16* wkh = wqh + tsz / 2;
        f16* wvh = wkh + tsz / 2;
        cvt_kernel<<<20480, 256, 0, stream>>>(x, wq, wk, wv, xh, wqh, wkh, wvh);
        // wqh/wkh/wvh are contiguous -> one stacked-W GEMM, N = 6144
        proj256_kernel<<<768, 512, 0, stream>>>(xh, wqh, cs, sn, qh, kh, vt);
    } else {
        proj_kernel<<<dim3(32, 16, 3), 256, 0, stream>>>(x, wq, wk, wv, qh, kh, vt);
        rope_kernel<<<dim3(16384, 2), 256, 0, stream>>>(qh, kh, cs, sn);
    }
    attn_kernel<<<512, 256, 0, stream>>>(qh, kh, vt, out);
}

// Round 6
// 316.186 us; speedup vs baseline: 1.5617x; 1.0141x over previous
//
#include <hip/hip_runtime.h>

#define Bc 2
#define Sc 2048
#define Dc 2048
#define Hc 16
#define DHc 128

typedef _Float16 f16;
typedef __attribute__((ext_vector_type(4))) _Float16 v4h;
typedef __attribute__((ext_vector_type(8))) _Float16 v8h;
typedef __attribute__((ext_vector_type(4))) float v4f;
typedef __attribute__((ext_vector_type(16))) float v16f;
typedef __attribute__((ext_vector_type(4))) float f32x4;

// ---------------------------------------------------------------------------
// Convert f32 inputs -> f16 once.
// ---------------------------------------------------------------------------
__global__ void cvt_kernel(const float* __restrict__ x, const float* __restrict__ wq,
                           const float* __restrict__ wk, const float* __restrict__ wv,
                           f16* __restrict__ xh, f16* __restrict__ wqh,
                           f16* __restrict__ wkh, f16* __restrict__ wvh)
{
    int bid = blockIdx.x;
    const float* src; f16* dst; int idx;
    if (bid < 8192)       { src = x;  dst = xh;  idx = bid; }
    else if (bid < 12288) { src = wq; dst = wqh; idx = bid - 8192; }
    else if (bid < 16384) { src = wk; dst = wkh; idx = bid - 12288; }
    else                  { src = wv; dst = wvh; idx = bid - 16384; }
    int i = idx * 256 + threadIdx.x;
    f32x4 v = ((const f32x4*)src)[i];
    v4h hv; hv[0]=(f16)v[0]; hv[1]=(f16)v[1]; hv[2]=(f16)v[2]; hv[3]=(f16)v[3];
    ((v4h*)dst)[i] = hv;
}

// ---------------------------------------------------------------------------
// Fused QKV projection GEMM C[4096][6144] = X . [wq;wk;wv]^T.
// 128x256 tile, BK=64, 8 waves, 768 blocks (3 exact rounds), T2 swizzle.
// Round 6: WITHIN-WAVE phase pipelining. r5's phases were {read frags ->
// MFMA on SAME frags}: dependent, so matrix pipe idled during every read
// burst (measured 2790 cyc/K-tile = MFMA 1242 + LDS 1500 fully serialized).
// Now each half-K-tile window does {STAGE / ds_read NEXT window's frags ->
// MFMA on CURRENT frags} with two named frag sets (64 VGPR, bounded —
// r2's 4-set variant spilled). 2 barriers/K-tile (asm s_barrier with
// "memory" clobber so reads can't hoist above the publish point).
// Counted vmcnt(6); 3-buffer LDS ring (144 KB).
// ---------------------------------------------------------------------------
__launch_bounds__(512, 2)
__global__ void proj256_kernel(const f16* __restrict__ xh, const f16* __restrict__ wall,
                               const float* __restrict__ cs, const float* __restrict__ sn,
                               f16* __restrict__ qh, f16* __restrict__ kh,
                               f16* __restrict__ vt)
{
    const int bid = blockIdx.x;
    const int swz = (bid & 7) * 96 + (bid >> 3);     // 768 % 8 == 0 -> bijective
    const int mt = swz & 31, nt = swz >> 5;
    const int m0 = mt * 128, n0 = nt * 256;

    const int tid = threadIdx.x;
    const int wid = tid >> 6, lane = tid & 63;
    const int wr = wid >> 2, wc = wid & 3;           // 2 x 4 waves
    const int l15 = lane & 15, quad = lane >> 4;
    const int x7 = l15 & 7;

    // LDS: 3 buffers x (A 128x64 + B 256x64) halves = 147456 B
    __shared__ __align__(16) f16 lds[73728];

    const f16* aS[2]; const f16* bS[4];
    #pragma unroll
    for (int j = 0; j < 2; ++j) {
        int c = tid + j * 512;
        int r = c >> 3, s = c & 7;
        aS[j] = xh + (size_t)(m0 + r) * Dc + ((s ^ (r & 7)) * 8);
    }
    #pragma unroll
    for (int j = 0; j < 4; ++j) {
        int c = tid + j * 512;
        int r = c >> 3, s = c & 7;
        bS[j] = wall + (size_t)(n0 + r) * Dc + ((s ^ (r & 7)) * 8);
    }

#define GLD(src_, dst_)                                                         \
    __builtin_amdgcn_global_load_lds(                                           \
        (const __attribute__((address_space(1))) void*)(src_),                  \
        (__attribute__((address_space(3))) void*)(dst_), 16, 0, 0)

#define STAGE(kt_, buf_) do {                                                   \
        const int _ko = (kt_) * 64;                                             \
        f16* _b = lds + (buf_) * 24576;                                         \
        GLD(aS[0] + _ko, _b + wid * 512);                                       \
        GLD(aS[1] + _ko, _b + 4096 + wid * 512);                                \
        GLD(bS[0] + _ko, _b + 8192 + wid * 512);                                \
        GLD(bS[1] + _ko, _b + 8192 + 4096  + wid * 512);                        \
        GLD(bS[2] + _ko, _b + 8192 + 8192  + wid * 512);                        \
        GLD(bS[3] + _ko, _b + 8192 + 12288 + wid * 512);                        \
    } while (0)

#define RDF(af_, bf_, buf_, kk_) do {                                           \
        const f16* _Ab = lds + (buf_) * 24576;                                  \
        const f16* _Bb = _Ab + 8192;                                            \
        _Pragma("unroll")                                                       \
        for (int mi = 0; mi < 4; ++mi)                                          \
            af_[mi] = *(const v8h*)(_Ab + (wr * 64 + mi * 16 + l15) * 64        \
                                    + ((((kk_) * 4 + quad) ^ x7) * 8));         \
        _Pragma("unroll")                                                       \
        for (int ni = 0; ni < 4; ++ni)                                          \
            bf_[ni] = *(const v8h*)(_Bb + (wc * 64 + ni * 16 + l15) * 64        \
                                    + ((((kk_) * 4 + quad) ^ x7) * 8));         \
    } while (0)

#define MM(af_, bf_) do {                                                       \
        __builtin_amdgcn_s_setprio(1);                                          \
        _Pragma("unroll")                                                       \
        for (int mi = 0; mi < 4; ++mi)                                          \
            _Pragma("unroll")                                                   \
            for (int ni = 0; ni < 4; ++ni)                                      \
                acc[mi][ni] = __builtin_amdgcn_mfma_f32_16x16x32_f16(           \
                    af_[mi], bf_[ni], acc[mi][ni], 0, 0, 0);                    \
        __builtin_amdgcn_s_setprio(0);                                          \
    } while (0)

#define VMW6  asm volatile("s_waitcnt vmcnt(6)"  ::: "memory")
#define VMW0  asm volatile("s_waitcnt vmcnt(0)"  ::: "memory")
#define BARM  asm volatile("s_barrier" ::: "memory")

    v4f acc[4][4];
    #pragma unroll
    for (int i = 0; i < 4; ++i)
        #pragma unroll
        for (int j = 0; j < 4; ++j)
            acc[i][j] = (v4f){0.f, 0.f, 0.f, 0.f};

    v8h af0[4], bf0[4], af1[4], bf1[4];

    // prologue: stage tiles 0,1; wait tile0; read tile0/kk0 frags
    STAGE(0, 0);
    STAGE(1, 1);
    VMW6;
    BARM;
    RDF(af0, bf0, 0, 0);

    int bR = 0, bN = 1, bS2 = 2;

    #pragma unroll 1
    for (int t = 0; t < 32; ++t) {
        // window A: MFMA tile t/kk0 (S0); read-ahead tile t/kk1 (S1); stage t+2
        BARM;                                // WAR guard for buf[(t+2)%3]
        if (t + 2 < 32) STAGE(t + 2, bS2);
        RDF(af1, bf1, bR, 1);
        MM(af0, bf0);
        // window B: MFMA tile t/kk1 (S1); read-ahead tile t+1/kk0 (S0)
        if (t + 1 < 32) {
            if (t + 2 < 32) { VMW6; } else { VMW0; }   // tile t+1 landed
            BARM;                            // publish buf[t+1]
            RDF(af0, bf0, bN, 0);
        }
        MM(af1, bf1);
        int tmp = bR; bR = bN; bN = bS2; bS2 = tmp;
    }
    __syncthreads();     // tile-31 frag reads (buf1) complete before Ep reuse

#undef STAGE
#undef GLD
#undef RDF
#undef MM
#undef VMW6
#undef VMW0
#undef BARM

    // ---------------- epilogue (z uniform per block: BN=256 | 2048) ---------
    const int z = n0 >> 11;
    const int bb = m0 >> 11, s0 = m0 & 2047;

    if (z < 2) {
        f16 (*Ep)[264] = (f16(*)[264])lds;
        #pragma unroll
        for (int mi = 0; mi < 4; ++mi)
            #pragma unroll
            for (int ni = 0; ni < 4; ++ni)
                #pragma unroll
                for (int r = 0; r < 4; ++r)
                    Ep[wr * 64 + mi * 16 + quad * 4 + r][wc * 64 + ni * 16 + l15] =
                        (f16)acc[mi][ni][r];
        __syncthreads();
        f16* outp = (z == 0) ? qh : kh;
        const float scl = (z == 0) ? 0.08838834764831845f : 1.0f;
        #pragma unroll
        for (int it = 0; it < 8; ++it) {
            int ch = tid + it * 512, row = ch >> 5, c = ch & 31;
            v8h val = *(const v8h*)&Ep[row][c * 8];
            int s = s0 + row;
            int nn = (n0 & 2047) + c * 8;
            int h = nn >> 7, d0 = nn & 127;
            const float* cp = cs + (size_t)s * DHc + d0;
            const float* sp = sn + (size_t)s * DHc + d0;
            f32x4 ca = *(const f32x4*)cp, cb = *(const f32x4*)(cp + 4);
            f32x4 sa = *(const f32x4*)sp, sb = *(const f32x4*)(sp + 4);
            float v[8];
            #pragma unroll
            for (int j = 0; j < 8; ++j) v[j] = (float)val[j];
            v8h rv;
            rv[0] = (f16)((v[0]*ca[0] - v[1]*sa[0]) * scl);
            rv[1] = (f16)((v[1]*ca[1] + v[0]*sa[1]) * scl);
            rv[2] = (f16)((v[2]*ca[2] - v[3]*sa[2]) * scl);
            rv[3] = (f16)((v[3]*ca[3] + v[2]*sa[3]) * scl);
            rv[4] = (f16)((v[4]*cb[0] - v[5]*sb[0]) * scl);
            rv[5] = (f16)((v[5]*cb[1] + v[4]*sb[1]) * scl);
            rv[6] = (f16)((v[6]*cb[2] - v[7]*sb[2]) * scl);
            rv[7] = (f16)((v[7]*cb[3] + v[6]*sb[3]) * scl);
            *(v8h*)(outp + ((size_t)(bb * Hc + h) * Sc + s) * DHc + d0) = rv;
        }
    } else {
        f16 (*Ep)[136] = (f16(*)[136])lds;
        #pragma unroll
        for (int mi = 0; mi < 4; ++mi)
            #pragma unroll
            for (int ni = 0; ni < 4; ++ni)
                #pragma unroll
                for (int r = 0; r < 4; ++r)
                    Ep[wc * 64 + ni * 16 + l15][wr * 64 + mi * 16 + quad * 4 + r] =
                        (f16)acc[mi][ni][r];
        __syncthreads();
        #pragma unroll
        for (int it = 0; it < 8; ++it) {
            int ch = tid + it * 512, n = ch >> 4, cm = ch & 15;
            int nn = (n0 & 2047) + n;
            int h = nn >> 7, d = nn & 127;
            int s = s0 + cm * 8;
            *(v8h*)(vt + ((size_t)(bb * Hc + h) * DHc + d) * Sc + s) =
                *(const v8h*)&Ep[n][cm * 8];
        }
    }
}

// ---------------------------------------------------------------------------
// Fallback proj (ws too small) + separate rope.
// ---------------------------------------------------------------------------
__launch_bounds__(256)
__global__ void proj_kernel(const float* __restrict__ x, const float* __restrict__ wq,
                            const float* __restrict__ wk, const float* __restrict__ wv,
                            f16* __restrict__ qh, f16* __restrict__ kh, f16* __restrict__ vt)
{
    const int z = blockIdx.z;
    const float* w = (z == 0) ? wq : ((z == 1) ? wk : wv);
    const int m0 = blockIdx.x * 128, n0 = blockIdx.y * 128;
    const int tid = threadIdx.x, lane = tid & 63, wid = tid >> 6;
    const int wm = wid >> 1, wn = wid & 1;
    const int l15 = lane & 15, quad = lane >> 4;

    __shared__ __align__(16) f16 smem[2 * 128 * 72];
    f16 (*As)[72] = (f16(*)[72])smem;
    f16 (*Bs)[72] = (f16(*)[72])(smem + 128 * 72);

    v4f acc[4][4];
    for (int i = 0; i < 4; ++i)
        for (int j = 0; j < 4; ++j)
            acc[i][j] = (v4f){0.f, 0.f, 0.f, 0.f};

    for (int k0 = 0; k0 < Dc; k0 += 64) {
        __syncthreads();
        for (int it = 0; it < 4; ++it) {
            int chunk = tid + it * 256;
            int r = chunk >> 3, cc = chunk & 7;
            const f32x4* pa = (const f32x4*)(x + (size_t)(m0 + r) * Dc + k0 + cc * 8);
            f32x4 a0 = pa[0], a1 = pa[1];
            v8h ha;
            ha[0]=(f16)a0[0]; ha[1]=(f16)a0[1]; ha[2]=(f16)a0[2]; ha[3]=(f16)a0[3];
            ha[4]=(f16)a1[0]; ha[5]=(f16)a1[1]; ha[6]=(f16)a1[2]; ha[7]=(f16)a1[3];
            *(v8h*)&As[r][cc * 8] = ha;
            const f32x4* pb = (const f32x4*)(w + (size_t)(n0 + r) * Dc + k0 + cc * 8);
            f32x4 b0 = pb[0], b1 = pb[1];
            v8h hb;
            hb[0]=(f16)b0[0]; hb[1]=(f16)b0[1]; hb[2]=(f16)b0[2]; hb[3]=(f16)b0[3];
            hb[4]=(f16)b1[0]; hb[5]=(f16)b1[1]; hb[6]=(f16)b1[2]; hb[7]=(f16)b1[3];
            *(v8h*)&Bs[r][cc * 8] = hb;
        }
        __syncthreads();
        for (int kk = 0; kk < 2; ++kk) {
            v8h af[4], bf[4];
            for (int mi = 0; mi < 4; ++mi)
                af[mi] = *(const v8h*)&As[wm * 64 + mi * 16 + l15][kk * 32 + quad * 8];
            for (int ni = 0; ni < 4; ++ni)
                bf[ni] = *(const v8h*)&Bs[wn * 64 + ni * 16 + l15][kk * 32 + quad * 8];
            for (int mi = 0; mi < 4; ++mi)
                for (int ni = 0; ni < 4; ++ni)
                    acc[mi][ni] = __builtin_amdgcn_mfma_f32_16x16x32_f16(
                        af[mi], bf[ni], acc[mi][ni], 0, 0, 0);
        }
    }
    __syncthreads();
    f16 (*Ep)[136] = (f16(*)[136])smem;
    for (int mi = 0; mi < 4; ++mi)
        for (int ni = 0; ni < 4; ++ni)
            for (int r = 0; r < 4; ++r) {
                int ml = wm * 64 + mi * 16 + quad * 4 + r;
                int nl = wn * 64 + ni * 16 + l15;
                f16 val = (f16)acc[mi][ni][r];
                if (z == 2) Ep[nl][ml] = val;
                else        Ep[ml][nl] = val;
            }
    __syncthreads();
    const int b = m0 >> 11, s0 = m0 & 2047, h = n0 >> 7;
    if (z < 2) {
        f16* outp = (z == 0) ? qh : kh;
        for (int it = 0; it < 8; ++it) {
            int ch = tid + it * 256, row = ch >> 4, c = ch & 15;
            *(v8h*)(outp + ((size_t)((b * Hc + h) * Sc) + s0 + row) * DHc + c * 8) =
                *(const v8h*)&Ep[row][c * 8];
        }
    } else {
        for (int it = 0; it < 8; ++it) {
            int ch = tid + it * 256, row = ch >> 4, c = ch & 15;
            *(v8h*)(vt + ((size_t)((b * Hc + h) * DHc) + row) * Sc + s0 + c * 8) =
                *(const v8h*)&Ep[row][c * 8];
        }
    }
}

__global__ void rope_kernel(f16* __restrict__ qh, f16* __restrict__ kh,
                            const float* __restrict__ cs, const float* __restrict__ sn)
{
    int i  = blockIdx.x * 256 + threadIdx.x;
    int d2 = i & 63;
    int s  = (i >> 6) & (Sc - 1);
    int bh = i >> 17;
    f16* t = blockIdx.y ? kh : qh;
    float scale = blockIdx.y ? 1.0f : 0.08838834764831845f;
    float c  = cs[s * DHc + 2 * d2];
    float sv = sn[s * DHc + 2 * d2];
    f16* p = t + ((size_t)bh * Sc + s) * DHc + 2 * d2;
    float t0 = (float)p[0], t1 = (float)p[1];
    p[0] = (f16)((t0 * c - t1 * sv) * scale);
    p[1] = (f16)((t1 * c + t0 * sv) * scale);
}

// ---------------------------------------------------------------------------
// Flash attention v6 (reverted): balanced + XCD-local, 256 blocks,
// each block does q-tiles {15-p, p} = exactly 34 KV-iters.
// (v7's 512-block re-grid measured ~8 us WORSE: attn is not TLP-starved.)
// ---------------------------------------------------------------------------
__launch_bounds__(256, 2)
__global__ void attn_kernel(const f16* __restrict__ qh, const f16* __restrict__ kh,
                            const f16* __restrict__ vt, float* __restrict__ out)
{
    const int L = blockIdx.x;
    const int slot = L >> 3;
    const int bh = (L & 7) * 4 + (slot >> 3);
    const int p  = slot & 7;
    const int b = bh >> 4, h = bh & 15;
    const int tid = threadIdx.x, lane = tid & 63, w = tid >> 6;
    const int l31 = lane & 31, half = lane >> 5;
    const int sw = l31 & 7;

    __shared__ __align__(16) f16 smem[32768];     // K dbuf 32KB + V dbuf 32KB
    f16* ksm = smem;
    f16* vsm = smem + 16384;

    const size_t bhoff = (size_t)bh * Sc * DHc;

    const f16* ksrc[4]; const f16* vsrc[4];
    f16* kdst[4]; f16* vdst[4];
    #pragma unroll
    for (int j = 0; j < 4; ++j) {
        int slot0 = j * 256 + w * 64;
        {   int r = (slot0 >> 4) + (lane >> 4);
            int c = (lane & 15) ^ (r & 7);
            ksrc[j] = kh + bhoff + (size_t)r * DHc + c * 8;
            kdst[j] = ksm + slot0 * 8; }
        {   int r = (slot0 >> 3) + (lane >> 3);
            int c = (lane & 7) ^ (r & 7);
            vsrc[j] = vt + bhoff + (size_t)r * Sc + c * 8;
            vdst[j] = vsm + slot0 * 8; }
    }

#define STAGE(kt_, buf_) do {                                                   \
        int _ko = (kt_) * 64 * DHc;                                             \
        int _vo = (kt_) * 64;                                                   \
        int _lb = (buf_) * 8192;                                                \
        _Pragma("unroll")                                                       \
        for (int j = 0; j < 4; ++j) {                                           \
            __builtin_amdgcn_global_load_lds(                                   \
                (const __attribute__((address_space(1))) void*)(ksrc[j] + _ko), \
                (__attribute__((address_space(3))) void*)(kdst[j] + _lb), 16, 0, 0); \
            __builtin_amdgcn_global_load_lds(                                   \
                (const __attribute__((address_space(1))) void*)(vsrc[j] + _vo), \
                (__attribute__((address_space(3))) void*)(vdst[j] + _lb), 16, 0, 0); \
        } } while (0)

    const int qtA = 15 - p;
    const int nktA = 2 * qtA + 2;     // + nktB = 34 for every block

    int ibuf = 0;
    STAGE(0, 0);

    #pragma unroll 1
    for (int ph = 0; ph < 2; ++ph) {
        const int qt  = ph ? p : qtA;
        const int nkt = 2 * qt + 2;
        const int q0  = qt * 128 + w * 32;
        const int qg  = q0 + l31;

        v8h qf[8];
        const f16* qrow = qh + bhoff + (size_t)qg * DHc;
        #pragma unroll
        for (int s = 0; s < 8; ++s)
            qf[s] = *(const v8h*)(qrow + s * 16 + half * 8);

        float l_run = 0.f;
        v16f o[4];
        #pragma unroll
        for (int i = 0; i < 4; ++i)
            #pragma unroll
            for (int r = 0; r < 16; ++r) o[i][r] = 0.f;

        #pragma unroll 1
        for (int kt = 0; kt < nkt; ++kt, ++ibuf) {
            __syncthreads();             // publishes buf[ibuf&1]
            const int buf = ibuf & 1;
            const int ni = ibuf + 1;
            if (ni < 34) {
                int tn = (ni < nktA) ? ni : ni - nktA;
                STAGE(tn, ni & 1);
            }
            if (q0 + 31 < kt * 64) continue;   // fully masked; barriers uniform

            const f16* kbuf = ksm + buf * 8192;
            const f16* vbuf = vsm + buf * 8192;
            const bool do1 = (kt * 64 + 32 <= q0 + 31);

            v16f st0, st1;
            #pragma unroll
            for (int r = 0; r < 16; ++r) { st0[r] = 0.f; st1[r] = 0.f; }
            #pragma unroll
            for (int s = 0; s < 8; ++s) {
                int c = ((s * 2 + half) ^ sw) * 8;
                v8h kf0 = *(const v8h*)(kbuf + l31 * 128 + c);
                st0 = __builtin_amdgcn_mfma_f32_32x32x16_f16(kf0, qf[s], st0, 0, 0, 0);
                if (do1) {
                    v8h kf1 = *(const v8h*)(kbuf + (32 + l31) * 128 + c);
                    st1 = __builtin_amdgcn_mfma_f32_32x32x16_f16(kf1, qf[s], st1, 0, 0, 0);
                }
            }

            float sum = 0.f;
            #pragma unroll
            for (int r = 0; r < 16; ++r) {
                int key = kt * 64 + (r & 3) + 8 * (r >> 2) + 4 * half;
                float sv = (key > qg) ? -1e30f : st0[r];
                float pe = __expf(sv);
                st0[r] = pe; sum += pe;
            }
            if (do1) {
                #pragma unroll
                for (int r = 0; r < 16; ++r) {
                    int key = kt * 64 + 32 + (r & 3) + 8 * (r >> 2) + 4 * half;
                    float sv = (key > qg) ? -1e30f : st1[r];
                    float pe = __expf(sv);
                    st1[r] = pe; sum += pe;
                }
            }
            sum += __shfl_xor(sum, 32);
            l_run += sum;

            #pragma unroll
            for (int s2 = 0; s2 < 4; ++s2) {
                v4h bfr;
                bfr[0]=(f16)st0[4*s2]; bfr[1]=(f16)st0[4*s2+1];
                bfr[2]=(f16)st0[4*s2+2]; bfr[3]=(f16)st0[4*s2+3];
                int c = ((s2 ^ sw) * 8) + half * 4;
                #pragma unroll
                for (int dt = 0; dt < 4; ++dt) {
                    v4h vf = *(const v4h*)(vbuf + (dt * 32 + l31) * 64 + c);
                    o[dt] = __builtin_amdgcn_mfma_f32_32x32x8f16(vf, bfr, o[dt], 0, 0, 0);
                }
            }
            if (do1) {
                #pragma unroll
                for (int s2 = 0; s2 < 4; ++s2) {
                    v4h bfr;
                    bfr[0]=(f16)st1[4*s2]; bfr[1]=(f16)st1[4*s2+1];
                    bfr[2]=(f16)st1[4*s2+2]; bfr[3]=(f16)st1[4*s2+3];
                    int c = (((4 + s2) ^ sw) * 8) + half * 4;
                    #pragma unroll
                    for (int dt = 0; dt < 4; ++dt) {
                        v4h vf = *(const v4h*)(vbuf + (dt * 32 + l31) * 64 + c);
                        o[dt] = __builtin_amdgcn_mfma_f32_32x32x8f16(vf, bfr, o[dt], 0, 0, 0);
                    }
                }
            }
        }

        float inv = 1.f / l_run;
        float mxd = -1e30f;
        #pragma unroll
        for (int dt = 0; dt < 4; ++dt)
            #pragma unroll
            for (int r = 0; r < 16; ++r) {
                o[dt][r] *= inv;
                mxd = fmaxf(mxd, o[dt][r]);
            }
        mxd = fmaxf(mxd, __shfl_xor(mxd, 32));
        float sd = 0.f;
        #pragma unroll
        for (int dt = 0; dt < 4; ++dt)
            #pragma unroll
            for (int r = 0; r < 16; ++r) {
                float t = __expf(o[dt][r] - mxd);
                o[dt][r] = t;
                sd += t;
            }
        sd += __shfl_xor(sd, 32);
        float rinv = 1.f / sd;

        float* orow = out + (size_t)(b * Sc + qg) * Dc + h * DHc;
        #pragma unroll
        for (int dt = 0; dt < 4; ++dt)
            #pragma unroll
            for (int g = 0; g < 4; ++g) {
                f32x4 vv;
                vv[0] = o[dt][4*g+0] * rinv;
                vv[1] = o[dt][4*g+1] * rinv;
                vv[2] = o[dt][4*g+2] * rinv;
                vv[3] = o[dt][4*g+3] * rinv;
                *(f32x4*)(orow + dt * 32 + g * 8 + half * 4) = vv;
            }
    }
#undef STAGE
}

extern "C" void kernel_launch(void* const* d_in, const int* in_sizes, int n_in,
                              void* d_out, int out_size, void* d_ws, size_t ws_size,
                              hipStream_t stream)
{
    const float* x  = (const float*)d_in[0];
    const float* wq = (const float*)d_in[1];
    const float* wk = (const float*)d_in[2];
    const float* wv = (const float*)d_in[3];
    const float* cs = (const float*)d_in[4];
    const float* sn = (const float*)d_in[5];
    float* out = (float*)d_out;

    const size_t tsz = (size_t)Bc * Hc * Sc * DHc;   // 8,388,608 halves
    f16* qh = (f16*)d_ws;
    f16* kh = qh + tsz;
    f16* vt = kh + tsz;

    if (ws_size >= 11 * tsz) {
        f16* xh  = vt + tsz;
        f16* wqh = xh + tsz;
        f16* wkh = wqh + tsz / 2;
        f16* wvh = wkh + tsz / 2;
        cvt_kernel<<<20480, 256, 0, stream>>>(x, wq, wk, wv, xh, wqh, wkh, wvh);
        // wqh/wkh/wvh are contiguous -> one stacked-W GEMM, N = 6144
        proj256_kernel<<<768, 512, 0, stream>>>(xh, wqh, cs, sn, qh, kh, vt);
    } else {
        proj_kernel<<<dim3(32, 16, 3), 256, 0, stream>>>(x, wq, wk, wv, qh, kh, vt);
        rope_kernel<<<dim3(16384, 2), 256, 0, stream>>>(qh, kh, cs, sn);
    }
    attn_kernel<<<256, 256, 0, stream>>>(qh, kh, vt, out);
}